// Round 4
// baseline (524.228 us; speedup 1.0000x reference)
//
#include <hip/hip_runtime.h>
#include <stdint.h>

#define EPSF 1e-6f

typedef unsigned short u16;
typedef __attribute__((ext_vector_type(8))) short short8;
typedef __attribute__((ext_vector_type(4))) float f32x4;

__device__ __forceinline__ float us2f(u16 u) {
  union { float f; unsigned int i; } c; c.i = ((unsigned int)u) << 16; return c.f;
}
__device__ __forceinline__ u16 f2bfu(float f) {
  union { float f; unsigned int i; } c; c.f = f;
  unsigned int i = c.i;
  return (u16)((i + 0x7FFFu + ((i >> 16) & 1u)) >> 16);
}
__device__ __forceinline__ float sigm(float x) { return 1.f / (1.f + __expf(-x)); }

typedef __attribute__((address_space(3))) unsigned int lds_u32;
typedef const __attribute__((address_space(1))) unsigned int glb_u32;
__device__ __forceinline__ void gl_lds16(const u16* g, u16* l) {
  __builtin_amdgcn_global_load_lds((glb_u32*)g, (lds_u32*)l, 16, 0, 0);
}

// ---------------- convert x (f32 -> bf16), 4 elems/thread ----------------
__global__ void k_cvt_x(const float* __restrict__ in, u16* __restrict__ out) {
  const int i = blockIdx.x * 256 + threadIdx.x;
  float4 v = ((const float4*)in)[i];
  ushort4 o;
  o.x = f2bfu(v.x); o.y = f2bfu(v.y); o.z = f2bfu(v.z); o.w = f2bfu(v.w);
  ((ushort4*)out)[i] = o;
}

// ---------------- transpose + convert: in f32 [R][C] -> out bf16 [C][R] ----------------
__global__ void k_transpose(const float* __restrict__ in, u16* __restrict__ out, int R, int C) {
  __shared__ float tile[32][33];
  const int tx = threadIdx.x & 31, ty = threadIdx.x >> 5;  // 32x8
  const int c0 = blockIdx.x << 5, r0 = blockIdx.y << 5;
  for (int i = ty; i < 32; i += 8) tile[i][tx] = in[(size_t)(r0 + i) * C + c0 + tx];
  __syncthreads();
  for (int i = ty; i < 32; i += 8) out[(size_t)(c0 + i) * R + r0 + tx] = f2bfu(tile[tx][i]);
}

// ---------------- GEMM: A[M][768] bf16 x BT[NC][768] bf16, 128x128 tile, BK=32 ----------------
// 3-deep LDS pipeline, counted vmcnt(4), raw s_barrier (no vmcnt(0) drain in loop).
// LDS col-group XOR swizzle keyed on (row>>1)&3: stage from pre-swizzled global
// source (global_load_lds writes linearly), read with the same XOR.
template <int MODE>
__global__ __launch_bounds__(256) void k_gemm(
    const u16* __restrict__ A, const u16* __restrict__ BT,
    const float* __restrict__ bias,
    u16* __restrict__ qo, u16* __restrict__ ko, u16* __restrict__ vo,
    float* __restrict__ outf)
{
  __shared__ __align__(16) u16 sA[3][128 * 32];
  __shared__ __align__(16) u16 sB[3][128 * 32];
  const int tid = threadIdx.x;
  const int lane = tid & 63;
  const int wid = tid >> 6;
  const int wr = wid >> 1, wc = wid & 1;
  // bijective XCD swizzle (nwg % 8 == 0 for both grids)
  const int nx = gridDim.x;
  int lid = blockIdx.y * nx + blockIdx.x;
  const int q8 = (nx * gridDim.y) >> 3;
  lid = (lid & 7) * q8 + (lid >> 3);
  const int m0 = (lid / nx) << 7;
  const int n0 = (lid % nx) << 7;
  const int srow = lane >> 2;                          // 0..15 (row within 16-row chunk)
  const int cgsw = ((lane & 3) ^ ((lane >> 3) & 3)) << 3;  // swizzled col-group (elems)

  const u16* ga0 = A  + (size_t)(m0 + (wid << 4) + srow) * 768 + cgsw;
  const u16* ga1 = A  + (size_t)(m0 + ((wid + 4) << 4) + srow) * 768 + cgsw;
  const u16* gb0 = BT + (size_t)(n0 + (wid << 4) + srow) * 768 + cgsw;
  const u16* gb1 = BT + (size_t)(n0 + ((wid + 4) << 4) + srow) * 768 + cgsw;

  f32x4 acc[4][4];
#pragma unroll
  for (int i = 0; i < 4; ++i)
#pragma unroll
    for (int j = 0; j < 4; ++j) acc[i][j] = (f32x4){0.f, 0.f, 0.f, 0.f};

#define STAGE(buf, ktel)                                        \
  do {                                                          \
    gl_lds16(ga0 + (ktel), &sA[buf][(wid) * 512]);              \
    gl_lds16(ga1 + (ktel), &sA[buf][(wid + 4) * 512]);          \
    gl_lds16(gb0 + (ktel), &sB[buf][(wid) * 512]);              \
    gl_lds16(gb1 + (ktel), &sB[buf][(wid + 4) * 512]);          \
  } while (0)

  const int r16 = lane & 15;
  // read-side swizzled k-slot: slot = (lane>>4) ^ ((row>>1)&3), row%16 == r16
  const int ksw = (((lane >> 4) ^ ((r16 >> 1) & 3)) << 3);

  // prologue: two stages in flight
  STAGE(0, 0);
  STAGE(1, 32);
  asm volatile("s_waitcnt vmcnt(4)" ::: "memory");   // stage(0) landed (mine)
  __builtin_amdgcn_s_barrier();                      // everyone's stage(0) landed

#define BODY(kt, buf)                                                          \
  do {                                                                         \
    STAGE((buf + 2) % 3, ((kt) + 2) * 32);                                     \
    const u16* pa = &sA[buf][0];                                               \
    const u16* pb = &sB[buf][0];                                               \
    short8 af[4], bfv[4];                                                      \
    _Pragma("unroll")                                                          \
    for (int i = 0; i < 4; ++i)                                                \
      af[i] = *(const short8*)(pa + ((wr << 6) + (i << 4) + r16) * 32 + ksw);  \
    _Pragma("unroll")                                                          \
    for (int j = 0; j < 4; ++j)                                                \
      bfv[j] = *(const short8*)(pb + ((wc << 6) + (j << 4) + r16) * 32 + ksw); \
    _Pragma("unroll")                                                          \
    for (int i = 0; i < 4; ++i)                                                \
      _Pragma("unroll")                                                        \
      for (int j = 0; j < 4; ++j)                                              \
        acc[i][j] = __builtin_amdgcn_mfma_f32_16x16x32_bf16(af[i], bfv[j], acc[i][j], 0, 0, 0); \
    asm volatile("s_waitcnt vmcnt(4) lgkmcnt(0)" ::: "memory");                \
    __builtin_amdgcn_sched_barrier(0);                                         \
    __builtin_amdgcn_s_barrier();                                              \
  } while (0)

  for (int ktb = 0; ktb < 24; ktb += 3) {
    BODY(ktb + 0, 0);
    BODY(ktb + 1, 1);
    BODY(ktb + 2, 2);
  }
#undef BODY
#undef STAGE
  asm volatile("s_waitcnt vmcnt(0)" ::: "memory");  // drain phantom stages before exit

#pragma unroll
  for (int i = 0; i < 4; ++i) {
    const int rowb = m0 + (wr << 6) + (i << 4) + ((lane >> 4) << 2);
#pragma unroll
    for (int j = 0; j < 4; ++j) {
      const int col = n0 + (wc << 6) + (j << 4) + r16;
      const float bcol = bias[col];
      if (MODE == 0) {
        const int s = (col >= 1536) ? 2 : ((col >= 768) ? 1 : 0);
        const int cr = col - s * 768;
        const int h = cr >> 6, d = cr & 63;
        u16* dst = (s == 0) ? qo : ((s == 1) ? ko : vo);
#pragma unroll
        for (int rg = 0; rg < 4; ++rg) {
          const int row = rowb + rg;
          const int b = row >> 12, n = row & 4095;
          float val = acc[i][j][rg] + bcol;
          if (s < 2) val = sigm(val);
          dst[(((size_t)(b * 12 + h) << 12) + n) * 64 + d] = f2bfu(val);
        }
      } else {
#pragma unroll
        for (int rg = 0; rg < 4; ++rg) {
          const int row = rowb + rg;
          outf[(size_t)row * 768 + col] = sigm(2.f * (acc[i][j][rg] + bcol));
        }
      }
    }
  }
}

// ---------------- qsum/ksum over N: coalesced 16B loads, LDS reduce, atomics ----------------
__global__ __launch_bounds__(256) void k_sums(const u16* __restrict__ q, const u16* __restrict__ k,
                                              float* __restrict__ qsum, float* __restrict__ ksum) {
  const int bh = blockIdx.x >> 3, sp = blockIdx.x & 7;
  const int tid = threadIdx.x;
  const int d8 = (tid & 7) << 3, nl = tid >> 3;  // 8 d-groups x 32 n-lanes
  const u16* qb = q + ((size_t)bh << 18);
  const u16* kb = k + ((size_t)bh << 18);
  float sq[8], sk[8];
#pragma unroll
  for (int u = 0; u < 8; ++u) { sq[u] = 0.f; sk[u] = 0.f; }
  for (int it = 0; it < 16; ++it) {
    const int n = (sp << 9) + (it << 5) + nl;
    short8 a = *(const short8*)(qb + ((size_t)n << 6) + d8);
    short8 b = *(const short8*)(kb + ((size_t)n << 6) + d8);
#pragma unroll
    for (int u = 0; u < 8; ++u) { sq[u] += us2f((u16)a[u]); sk[u] += us2f((u16)b[u]); }
  }
  __shared__ float rq[32][68];
  __shared__ float rk[32][68];
#pragma unroll
  for (int u = 0; u < 8; ++u) { rq[nl][d8 + u] = sq[u]; rk[nl][d8 + u] = sk[u]; }
  __syncthreads();
  if (tid < 128) {
    const int which = tid >> 6, d = tid & 63;
    float s = 0.f;
    if (which == 0) {
#pragma unroll
      for (int g = 0; g < 32; ++g) s += rq[g][d];
      atomicAdd(&qsum[(bh << 6) + d], s);
    } else {
#pragma unroll
      for (int g = 0; g < 32; ++g) s += rk[g][d];
      atomicAdd(&ksum[(bh << 6) + d], s);
    }
  }
}

// ---------------- si/so + qsi/kso ----------------
__global__ __launch_bounds__(256) void k_flow1(
    const u16* __restrict__ q, const u16* __restrict__ k,
    const float* __restrict__ qsum, const float* __restrict__ ksum,
    float* __restrict__ si_out, float* __restrict__ qsi, float* __restrict__ kso)
{
  const int bh = blockIdx.x >> 3, sp = blockIdx.x & 7;
  const int lane = threadIdx.x & 63, wid = threadIdx.x >> 6;
  const int j = lane & 15;
  const int grp = (wid << 2) | (lane >> 4);
  const u16* qb = q + ((size_t)bh << 18);
  const u16* kb = k + ((size_t)bh << 18);
  float ke[4], qe[4];
#pragma unroll
  for (int t = 0; t < 4; ++t) {
    ke[t] = ksum[(bh << 6) + (j << 2) + t] + EPSF;
    qe[t] = qsum[(bh << 6) + (j << 2) + t] + EPSF;
  }
  float Sk = ke[0] + ke[1] + ke[2] + ke[3];
  float Sq = qe[0] + qe[1] + qe[2] + qe[3];
#pragma unroll
  for (int msk = 1; msk < 16; msk <<= 1) { Sk += __shfl_xor(Sk, msk, 64); Sq += __shfl_xor(Sq, msk, 64); }
  const float cK = EPSF * Sk + EPSF;
  const float cQ = EPSF * Sq + EPSF;
  float aq0 = 0, aq1 = 0, aq2 = 0, aq3 = 0, ak0 = 0, ak1 = 0, ak2 = 0, ak3 = 0;
  const int nbase = sp << 9;
  for (int it = 0; it < 32; ++it) {
    const int n = nbase + (it << 4) + grp;
    const uint64_t lq = *(const uint64_t*)(qb + ((size_t)n << 6) + (j << 2));
    const uint64_t lk = *(const uint64_t*)(kb + ((size_t)n << 6) + (j << 2));
    const float q0 = us2f((u16)lq), q1 = us2f((u16)(lq >> 16)), q2 = us2f((u16)(lq >> 32)), q3 = us2f((u16)(lq >> 48));
    const float k0 = us2f((u16)lk), k1 = us2f((u16)(lk >> 16)), k2 = us2f((u16)(lk >> 32)), k3 = us2f((u16)(lk >> 48));
    float dq = q0 * ke[0] + q1 * ke[1] + q2 * ke[2] + q3 * ke[3];
    float dk = k0 * qe[0] + k1 * qe[1] + k2 * qe[2] + k3 * qe[3];
#pragma unroll
    for (int msk = 1; msk < 16; msk <<= 1) { dq += __shfl_xor(dq, msk, 64); dk += __shfl_xor(dk, msk, 64); }
    const float si = 1.f / (dq + cK);
    const float so = 1.f / (dk + cQ);
    if (j == 0) si_out[(bh << 12) + n] = si;
    aq0 += q0 * si; aq1 += q1 * si; aq2 += q2 * si; aq3 += q3 * si;
    ak0 += k0 * so; ak1 += k1 * so; ak2 += k2 * so; ak3 += k3 * so;
  }
  __shared__ float redq[16][64];
  __shared__ float redk[16][64];
  redq[grp][(j << 2) + 0] = aq0; redq[grp][(j << 2) + 1] = aq1;
  redq[grp][(j << 2) + 2] = aq2; redq[grp][(j << 2) + 3] = aq3;
  redk[grp][(j << 2) + 0] = ak0; redk[grp][(j << 2) + 1] = ak1;
  redk[grp][(j << 2) + 2] = ak2; redk[grp][(j << 2) + 3] = ak3;
  __syncthreads();
  if (threadIdx.x < 64) {
    float s1 = 0.f, s2 = 0.f;
#pragma unroll
    for (int g = 0; g < 16; ++g) { s1 += redq[g][threadIdx.x]; s2 += redk[g][threadIdx.x]; }
    atomicAdd(&qsi[(bh << 6) + threadIdx.x], s1);
    atomicAdd(&kso[(bh << 6) + threadIdx.x], s2);
  }
}

// ---------------- conserved sink/source -> m = si*sigmoid(cs); e = exp(clip(csrc)); sumexp ----------------
__global__ __launch_bounds__(256) void k_flow2(
    const u16* __restrict__ q, const u16* __restrict__ k,
    const float* __restrict__ qsi, const float* __restrict__ kso,
    const float* __restrict__ si_in,
    float* __restrict__ mo, float* __restrict__ eo, float* __restrict__ sumexp)
{
  const int bh = blockIdx.x >> 3, sp = blockIdx.x & 7;
  const int lane = threadIdx.x & 63, wid = threadIdx.x >> 6;
  const int j = lane & 15;
  const int grp = (wid << 2) | (lane >> 4);
  const u16* qb = q + ((size_t)bh << 18);
  const u16* kb = k + ((size_t)bh << 18);
  float soe[4], qie[4];
#pragma unroll
  for (int t = 0; t < 4; ++t) {
    soe[t] = kso[(bh << 6) + (j << 2) + t] + EPSF;
    qie[t] = qsi[(bh << 6) + (j << 2) + t] + EPSF;
  }
  float Ss = soe[0] + soe[1] + soe[2] + soe[3];
  float Si = qie[0] + qie[1] + qie[2] + qie[3];
#pragma unroll
  for (int msk = 1; msk < 16; msk <<= 1) { Ss += __shfl_xor(Ss, msk, 64); Si += __shfl_xor(Si, msk, 64); }
  const float cS = EPSF * Ss + EPSF;
  const float cR = EPSF * Si + EPSF;
  float esum = 0.f;
  const int nbase = sp << 9;
  for (int it = 0; it < 32; ++it) {
    const int n = nbase + (it << 4) + grp;
    const uint64_t lq = *(const uint64_t*)(qb + ((size_t)n << 6) + (j << 2));
    const uint64_t lk = *(const uint64_t*)(kb + ((size_t)n << 6) + (j << 2));
    const float q0 = us2f((u16)lq), q1 = us2f((u16)(lq >> 16)), q2 = us2f((u16)(lq >> 32)), q3 = us2f((u16)(lq >> 48));
    const float k0 = us2f((u16)lk), k1 = us2f((u16)(lk >> 16)), k2 = us2f((u16)(lk >> 32)), k3 = us2f((u16)(lk >> 48));
    float cs = q0 * soe[0] + q1 * soe[1] + q2 * soe[2] + q3 * soe[3];
    float cr = k0 * qie[0] + k1 * qie[1] + k2 * qie[2] + k3 * qie[3];
#pragma unroll
    for (int msk = 1; msk < 16; msk <<= 1) { cs += __shfl_xor(cs, msk, 64); cr += __shfl_xor(cr, msk, 64); }
    cs += cS;
    cr += cR;
    cr = fminf(1.f, fmaxf(-1.f, cr));
    const float ev = __expf(cr);
    if (j == 0) {
      const float sa = sigm(cs);
      mo[(bh << 12) + n] = si_in[(bh << 12) + n] * sa;
      eo[(bh << 12) + n] = ev;
      esum += ev;
    }
  }
  __shared__ float red[16];
  if (j == 0) red[grp] = esum;
  __syncthreads();
  if (threadIdx.x == 0) {
    float s = 0.f;
#pragma unroll
    for (int g = 0; g < 16; ++g) s += red[g];
    atomicAdd(&sumexp[bh], s);
  }
}

// ---------------- kv via MFMA: kvm[d][e] = sum_n (k[n,d]*e[n]) * v[n,e] ----------------
__global__ __launch_bounds__(256) void k_kv(
    const u16* __restrict__ k, const u16* __restrict__ v,
    const float* __restrict__ e_arr, float* __restrict__ kvm)
{
  __shared__ __align__(16) u16 smem[2 * 64 * 136];  // 34816 B; reused as f32 reduce buf
  u16* kT = smem;
  u16* vT = smem + 64 * 136;
  const int tid = threadIdx.x;
  const int bh = blockIdx.x >> 3, sp = blockIdx.x & 7;
  const int lane = tid & 63, wid = tid >> 6;
  const int r16 = lane & 15, g = lane >> 4;
  const u16* kb = k + ((size_t)bh << 18);
  const u16* vb = v + ((size_t)bh << 18);
  const float* eb = e_arr + ((size_t)bh << 12);

  f32x4 acc[4][4];
#pragma unroll
  for (int i = 0; i < 4; ++i)
#pragma unroll
    for (int j = 0; j < 4; ++j) acc[i][j] = (f32x4){0.f, 0.f, 0.f, 0.f};

  const int nf = (wid << 5) + (g << 3);  // wave n-window + lane-group k offset

  for (int st = 0; st < 4; ++st) {
    const int nst = (sp << 9) + (st << 7);
#pragma unroll
    for (int i = 0; i < 4; ++i) {
      const int c = tid + (i << 8);
      const int nl = c >> 3;              // 0..127
      const int d0 = (c & 7) << 3;        // 0..56
      const int ng = nst + nl;
      short8 k8 = *(const short8*)(kb + ((size_t)ng << 6) + d0);
      short8 v8 = *(const short8*)(vb + ((size_t)ng << 6) + d0);
      const float en = eb[ng];
      const int col = nl ^ (d0 & 56);     // XOR key ((d0>>3)&7)<<3 == d0&56
#pragma unroll
      for (int u = 0; u < 8; ++u) {
        kT[(d0 + u) * 136 + col] = f2bfu(us2f((u16)k8[u]) * en);
        vT[(d0 + u) * 136 + col] = (u16)(unsigned short)v8[u];
      }
    }
    __syncthreads();

    short8 af[4], bf[4];
#pragma unroll
    for (int mi = 0; mi < 4; ++mi) {
      const int row = (mi << 4) + r16;
      af[mi] = *(const short8*)&kT[row * 136 + (nf ^ (row & 56))];
    }
#pragma unroll
    for (int nj = 0; nj < 4; ++nj) {
      const int row = (nj << 4) + r16;
      bf[nj] = *(const short8*)&vT[row * 136 + (nf ^ (row & 56))];
    }
#pragma unroll
    for (int mi = 0; mi < 4; ++mi)
#pragma unroll
      for (int nj = 0; nj < 4; ++nj)
        acc[mi][nj] = __builtin_amdgcn_mfma_f32_16x16x32_bf16(af[mi], bf[nj], acc[mi][nj], 0, 0, 0);
    __syncthreads();
  }

  // cross-wave reduce (two 32-d halves through LDS) + coalesced atomics
  float* red = (float*)smem;
  float* kvb = kvm + ((size_t)bh << 12);
#pragma unroll
  for (int half = 0; half < 2; ++half) {
#pragma unroll
    for (int m2 = 0; m2 < 2; ++m2) {
      const int mi = (half << 1) + m2;
#pragma unroll
      for (int nj = 0; nj < 4; ++nj)
#pragma unroll
        for (int rg = 0; rg < 4; ++rg)
          red[(wid << 11) + (((m2 << 4) + (g << 2) + rg) << 6) + (nj << 4) + r16] = acc[mi][nj][rg];
    }
    __syncthreads();
    const int base = tid << 3;
#pragma unroll
    for (int u2 = 0; u2 < 2; ++u2) {
      const int o = base + (u2 << 2);
      float4 s0 = *(const float4*)&red[o];
      float4 s1 = *(const float4*)&red[2048 + o];
      float4 s2 = *(const float4*)&red[4096 + o];
      float4 s3 = *(const float4*)&red[6144 + o];
      s0.x += s1.x + s2.x + s3.x;
      s0.y += s1.y + s2.y + s3.y;
      s0.z += s1.z + s2.z + s3.z;
      s0.w += s1.w + s2.w + s3.w;
      const int gi = (half << 11) + o;
      atomicAdd(&kvb[gi + 0], s0.x);
      atomicAdd(&kvb[gi + 1], s0.y);
      atomicAdd(&kvb[gi + 2], s0.z);
      atomicAdd(&kvb[gi + 3], s0.w);
    }
    __syncthreads();
  }
}

// ---------------- x_update = (q @ kv) * m[n] * scale -> attn [B][N][C] bf16 (MFMA) ----------------
__global__ __launch_bounds__(256) void k_xup(
    const u16* __restrict__ q, const float* __restrict__ kvm,
    const float* __restrict__ m_arr, const float* __restrict__ sumexp,
    u16* __restrict__ attn)
{
  const int bh = blockIdx.y;
  const int n0 = blockIdx.x << 7;
  const int b = bh / 12, h = bh % 12;
  __shared__ __align__(16) u16 qs[128 * 72];   // stride 72 elems (144B): 2-way banks, 16B aligned
  __shared__ __align__(16) u16 kvs[64 * 72];   // kv^T as [e][d] bf16
  const int tid = threadIdx.x, lane = tid & 63, wid = tid >> 6;
  const u16* qg = q + ((size_t)bh << 18) + ((size_t)n0 << 6);
#pragma unroll
  for (int i = 0; i < 4; ++i) {
    const int c = tid + (i << 8);
    const int nl = c >> 3, d0 = (c & 7) << 3;
    *(short8*)&qs[nl * 72 + d0] = *(const short8*)(qg + (nl << 6) + d0);
  }
  const float* kvg = kvm + ((size_t)bh << 12);
#pragma unroll
  for (int i = 0; i < 4; ++i) {
    const int idx = (tid << 2) + (i << 10);
    const int d = idx >> 6, e0 = idx & 63;
    float4 vv = *(const float4*)(kvg + idx);
    kvs[(e0 + 0) * 72 + d] = f2bfu(vv.x);
    kvs[(e0 + 1) * 72 + d] = f2bfu(vv.y);
    kvs[(e0 + 2) * 72 + d] = f2bfu(vv.z);
    kvs[(e0 + 3) * 72 + d] = f2bfu(vv.w);
  }
  __syncthreads();
  const float scale = 4096.f / sumexp[bh];
  const int r16 = lane & 15, kg8 = (lane >> 4) << 3;
  f32x4 acc[2][4];
#pragma unroll
  for (int i = 0; i < 2; ++i)
#pragma unroll
    for (int j = 0; j < 4; ++j) acc[i][j] = (f32x4){0.f, 0.f, 0.f, 0.f};
#pragma unroll
  for (int kk = 0; kk < 2; ++kk) {
    short8 af[2], bfv[4];
#pragma unroll
    for (int mi = 0; mi < 2; ++mi)
      af[mi] = *(const short8*)&qs[((wid << 5) + (mi << 4) + r16) * 72 + (kk << 5) + kg8];
#pragma unroll
    for (int nj = 0; nj < 4; ++nj)
      bfv[nj] = *(const short8*)&kvs[((nj << 4) + r16) * 72 + (kk << 5) + kg8];
#pragma unroll
    for (int mi = 0; mi < 2; ++mi)
#pragma unroll
      for (int nj = 0; nj < 4; ++nj)
        acc[mi][nj] = __builtin_amdgcn_mfma_f32_16x16x32_bf16(af[mi], bfv[nj], acc[mi][nj], 0, 0, 0);
  }
#pragma unroll
  for (int mi = 0; mi < 2; ++mi) {
#pragma unroll
    for (int rg = 0; rg < 4; ++rg) {
      const int n = n0 + (wid << 5) + (mi << 4) + ((lane >> 4) << 2) + rg;
      const float mult = m_arr[((size_t)bh << 12) + n] * scale;
#pragma unroll
      for (int nj = 0; nj < 4; ++nj) {
        const int e = (nj << 4) + r16;
        attn[((size_t)(b * 4096 + n)) * 768 + (h << 6) + e] = f2bfu(acc[mi][nj][rg] * mult);
      }
    }
  }
}

extern "C" void kernel_launch(void* const* d_in, const int* in_sizes, int n_in,
                              void* d_out, int out_size, void* d_ws, size_t ws_size,
                              hipStream_t stream)
{
  (void)in_sizes; (void)n_in; (void)out_size; (void)ws_size;
  const float* x     = (const float*)d_in[0];
  const float* Wqkv  = (const float*)d_in[1];
  const float* bqkv  = (const float*)d_in[2];
  const float* Wproj = (const float*)d_in[3];
  const float* bproj = (const float*)d_in[4];
  float* out = (float*)d_out;

  char* ws = (char*)d_ws;
  size_t off = 0;
  auto alloc = [&](size_t bytes) -> char* {
    char* p = ws + off;
    off += (bytes + 255) & ~(size_t)255;
    return p;
  };
  u16* q    = (u16*)alloc(50331648);       // [B,H,N,D] bf16
  u16* k    = (u16*)alloc(50331648);
  u16* v    = (u16*)alloc(50331648);
  u16* xbf  = (u16*)alloc(50331648);       // x bf16; reused as attn output
  u16* WqT  = (u16*)alloc(3538944);        // [2304][768] bf16
  u16* WpT  = (u16*)alloc(1179648);        // [768][768] bf16
  float* si = (float*)alloc(1572864);      // [B*H][N]
  float* mb = (float*)alloc(1572864);      // si * sink_allocation
  float* eb = (float*)alloc(1572864);      // exp(clipped conserved_source)
  char* zbase = ws + off;
  float* qsum   = (float*)alloc(24576);
  float* ksum   = (float*)alloc(24576);
  float* qsi    = (float*)alloc(24576);
  float* kso    = (float*)alloc(24576);
  float* sumexp = (float*)alloc(512);
  float* kvm    = (float*)alloc(1572864);  // [B*H][64 d][64 e] f32
  const size_t zbytes = (size_t)((ws + off) - zbase);

  hipMemsetAsync(zbase, 0, zbytes, stream);
  k_cvt_x<<<24576, 256, 0, stream>>>(x, xbf);
  k_transpose<<<dim3(72, 24), 256, 0, stream>>>(Wqkv, WqT, 768, 2304);
  k_transpose<<<dim3(24, 24), 256, 0, stream>>>(Wproj, WpT, 768, 768);
  k_gemm<0><<<dim3(18, 256), 256, 0, stream>>>(xbf, WqT, bqkv, q, k, v, nullptr);
  k_sums<<<768, 256, 0, stream>>>(q, k, qsum, ksum);
  k_flow1<<<768, 256, 0, stream>>>(q, k, qsum, ksum, si, qsi, kso);
  k_flow2<<<768, 256, 0, stream>>>(q, k, qsi, kso, si, mb, eb, sumexp);
  k_kv<<<768, 256, 0, stream>>>(k, v, eb, kvm);
  k_xup<<<dim3(32, 96), 256, 0, stream>>>(q, kvm, mb, sumexp, xbf);
  k_gemm<1><<<dim3(6, 256), 256, 0, stream>>>(xbf, WpT, bproj, nullptr, nullptr, nullptr, out);
}

// Round 5
// 477.343 us; speedup vs baseline: 1.0982x; 1.0982x over previous
//
#include <hip/hip_runtime.h>
#include <stdint.h>

#define EPSF 1e-6f

typedef unsigned short u16;
typedef __attribute__((ext_vector_type(8))) short short8;
typedef __attribute__((ext_vector_type(4))) float f32x4;

__device__ __forceinline__ float us2f(u16 u) {
  union { float f; unsigned int i; } c; c.i = ((unsigned int)u) << 16; return c.f;
}
__device__ __forceinline__ u16 f2bfu(float f) {
  union { float f; unsigned int i; } c; c.f = f;
  unsigned int i = c.i;
  return (u16)((i + 0x7FFFu + ((i >> 16) & 1u)) >> 16);
}
__device__ __forceinline__ float sigm(float x) { return 1.f / (1.f + __expf(-x)); }

typedef __attribute__((address_space(3))) unsigned int lds_u32;
typedef const __attribute__((address_space(1))) unsigned int glb_u32;
__device__ __forceinline__ void gl_lds16(const u16* g, u16* l) {
  __builtin_amdgcn_global_load_lds((glb_u32*)g, (lds_u32*)l, 16, 0, 0);
}

// ---------------- convert x (f32 -> bf16), 4 elems/thread ----------------
__global__ void k_cvt_x(const float* __restrict__ in, u16* __restrict__ out) {
  const int i = blockIdx.x * 256 + threadIdx.x;
  float4 v = ((const float4*)in)[i];
  ushort4 o;
  o.x = f2bfu(v.x); o.y = f2bfu(v.y); o.z = f2bfu(v.z); o.w = f2bfu(v.w);
  ((ushort4*)out)[i] = o;
}

// ---------------- transpose + convert: in f32 [R][C] -> out bf16 [C][R] ----------------
__global__ void k_transpose(const float* __restrict__ in, u16* __restrict__ out, int R, int C) {
  __shared__ float tile[32][33];
  const int tx = threadIdx.x & 31, ty = threadIdx.x >> 5;  // 32x8
  const int c0 = blockIdx.x << 5, r0 = blockIdx.y << 5;
  for (int i = ty; i < 32; i += 8) tile[i][tx] = in[(size_t)(r0 + i) * C + c0 + tx];
  __syncthreads();
  for (int i = ty; i < 32; i += 8) out[(size_t)(c0 + i) * R + r0 + tx] = f2bfu(tile[tx][i]);
}

// ---------------- GEMM: A[M][768] bf16 x BT[NC][768] bf16, 128x128 tile, BK=32 ----------------
// Round-3 2-buffer pipeline (32KB LDS, proven occupancy) + round-4 XOR swizzle
// (proven conflict-free): stage from pre-swizzled global source, read with same XOR.
template <int MODE>
__global__ __launch_bounds__(256) void k_gemm(
    const u16* __restrict__ A, const u16* __restrict__ BT,
    const float* __restrict__ bias,
    u16* __restrict__ qo, u16* __restrict__ ko, u16* __restrict__ vo,
    float* __restrict__ outf)
{
  __shared__ __align__(16) u16 sA[2][128 * 32];
  __shared__ __align__(16) u16 sB[2][128 * 32];
  const int tid = threadIdx.x;
  const int lane = tid & 63;
  const int wid = tid >> 6;
  const int wr = wid >> 1, wc = wid & 1;
  // bijective XCD swizzle (nwg % 8 == 0 for both grids)
  const int nx = gridDim.x;
  int lid = blockIdx.y * nx + blockIdx.x;
  const int q8 = (nx * gridDim.y) >> 3;
  lid = (lid & 7) * q8 + (lid >> 3);
  const int m0 = (lid / nx) << 7;
  const int n0 = (lid % nx) << 7;
  const int srow = lane >> 2;                              // 0..15 (row within 16-row chunk)
  const int cgsw = ((lane & 3) ^ ((lane >> 3) & 3)) << 3;  // pre-swizzled col-group (elems)

  const u16* ga0 = A  + (size_t)(m0 + (wid << 4) + srow) * 768 + cgsw;
  const u16* ga1 = A  + (size_t)(m0 + ((wid + 4) << 4) + srow) * 768 + cgsw;
  const u16* gb0 = BT + (size_t)(n0 + (wid << 4) + srow) * 768 + cgsw;
  const u16* gb1 = BT + (size_t)(n0 + ((wid + 4) << 4) + srow) * 768 + cgsw;

  f32x4 acc[4][4];
#pragma unroll
  for (int i = 0; i < 4; ++i)
#pragma unroll
    for (int j = 0; j < 4; ++j) acc[i][j] = (f32x4){0.f, 0.f, 0.f, 0.f};

#define STAGE(buf, ktel)                                        \
  do {                                                          \
    gl_lds16(ga0 + (ktel), &sA[buf][(wid) * 512]);              \
    gl_lds16(ga1 + (ktel), &sA[buf][(wid + 4) * 512]);          \
    gl_lds16(gb0 + (ktel), &sB[buf][(wid) * 512]);              \
    gl_lds16(gb1 + (ktel), &sB[buf][(wid + 4) * 512]);          \
  } while (0)

  STAGE(0, 0);
  asm volatile("s_waitcnt vmcnt(0)" ::: "memory");
  __syncthreads();

  const int r16 = lane & 15;
  // read-side swizzled k-slot: slot = (lane>>4) ^ ((row>>1)&3), row%16 == r16
  const int ksw = (((lane >> 4) ^ ((r16 >> 1) & 3)) << 3);
  int cur = 0;
  for (int kt = 1; kt <= 24; ++kt) {
    if (kt < 24) {
      if (cur) STAGE(0, kt * 32); else STAGE(1, kt * 32);
    }
    const u16* pa = &sA[cur][0];
    const u16* pb = &sB[cur][0];
    short8 af[4], bfv[4];
#pragma unroll
    for (int i = 0; i < 4; ++i)
      af[i] = *(const short8*)(pa + ((wr << 6) + (i << 4) + r16) * 32 + ksw);
#pragma unroll
    for (int j = 0; j < 4; ++j)
      bfv[j] = *(const short8*)(pb + ((wc << 6) + (j << 4) + r16) * 32 + ksw);
#pragma unroll
    for (int i = 0; i < 4; ++i)
#pragma unroll
      for (int j = 0; j < 4; ++j)
        acc[i][j] = __builtin_amdgcn_mfma_f32_16x16x32_bf16(af[i], bfv[j], acc[i][j], 0, 0, 0);
    asm volatile("s_waitcnt vmcnt(0)" ::: "memory");
    __syncthreads();
    cur ^= 1;
  }
#undef STAGE

#pragma unroll
  for (int i = 0; i < 4; ++i) {
    const int rowb = m0 + (wr << 6) + (i << 4) + ((lane >> 4) << 2);
#pragma unroll
    for (int j = 0; j < 4; ++j) {
      const int col = n0 + (wc << 6) + (j << 4) + r16;
      const float bcol = bias[col];
      if (MODE == 0) {
        const int s = (col >= 1536) ? 2 : ((col >= 768) ? 1 : 0);
        const int cr = col - s * 768;
        const int h = cr >> 6, d = cr & 63;
        u16* dst = (s == 0) ? qo : ((s == 1) ? ko : vo);
#pragma unroll
        for (int rg = 0; rg < 4; ++rg) {
          const int row = rowb + rg;
          const int b = row >> 12, n = row & 4095;
          float val = acc[i][j][rg] + bcol;
          if (s < 2) val = sigm(val);
          dst[(((size_t)(b * 12 + h) << 12) + n) * 64 + d] = f2bfu(val);
        }
      } else {
#pragma unroll
        for (int rg = 0; rg < 4; ++rg) {
          const int row = rowb + rg;
          outf[(size_t)row * 768 + col] = sigm(2.f * (acc[i][j][rg] + bcol));
        }
      }
    }
  }
}

// ---------------- qsum/ksum over N: coalesced 16B loads, LDS reduce, atomics ----------------
__global__ __launch_bounds__(256) void k_sums(const u16* __restrict__ q, const u16* __restrict__ k,
                                              float* __restrict__ qsum, float* __restrict__ ksum) {
  const int bh = blockIdx.x >> 3, sp = blockIdx.x & 7;
  const int tid = threadIdx.x;
  const int d8 = (tid & 7) << 3, nl = tid >> 3;  // 8 d-groups x 32 n-lanes
  const u16* qb = q + ((size_t)bh << 18);
  const u16* kb = k + ((size_t)bh << 18);
  float sq[8], sk[8];
#pragma unroll
  for (int u = 0; u < 8; ++u) { sq[u] = 0.f; sk[u] = 0.f; }
  for (int it = 0; it < 16; ++it) {
    const int n = (sp << 9) + (it << 5) + nl;
    short8 a = *(const short8*)(qb + ((size_t)n << 6) + d8);
    short8 b = *(const short8*)(kb + ((size_t)n << 6) + d8);
#pragma unroll
    for (int u = 0; u < 8; ++u) { sq[u] += us2f((u16)a[u]); sk[u] += us2f((u16)b[u]); }
  }
  __shared__ float rq[32][68];
  __shared__ float rk[32][68];
#pragma unroll
  for (int u = 0; u < 8; ++u) { rq[nl][d8 + u] = sq[u]; rk[nl][d8 + u] = sk[u]; }
  __syncthreads();
  if (tid < 128) {
    const int which = tid >> 6, d = tid & 63;
    float s = 0.f;
    if (which == 0) {
#pragma unroll
      for (int g = 0; g < 32; ++g) s += rq[g][d];
      atomicAdd(&qsum[(bh << 6) + d], s);
    } else {
#pragma unroll
      for (int g = 0; g < 32; ++g) s += rk[g][d];
      atomicAdd(&ksum[(bh << 6) + d], s);
    }
  }
}

// ---------------- si/so + qsi/kso ----------------
__global__ __launch_bounds__(256) void k_flow1(
    const u16* __restrict__ q, const u16* __restrict__ k,
    const float* __restrict__ qsum, const float* __restrict__ ksum,
    float* __restrict__ si_out, float* __restrict__ qsi, float* __restrict__ kso)
{
  const int bh = blockIdx.x >> 3, sp = blockIdx.x & 7;
  const int lane = threadIdx.x & 63, wid = threadIdx.x >> 6;
  const int j = lane & 15;
  const int grp = (wid << 2) | (lane >> 4);
  const u16* qb = q + ((size_t)bh << 18);
  const u16* kb = k + ((size_t)bh << 18);
  float ke[4], qe[4];
#pragma unroll
  for (int t = 0; t < 4; ++t) {
    ke[t] = ksum[(bh << 6) + (j << 2) + t] + EPSF;
    qe[t] = qsum[(bh << 6) + (j << 2) + t] + EPSF;
  }
  float Sk = ke[0] + ke[1] + ke[2] + ke[3];
  float Sq = qe[0] + qe[1] + qe[2] + qe[3];
#pragma unroll
  for (int msk = 1; msk < 16; msk <<= 1) { Sk += __shfl_xor(Sk, msk, 64); Sq += __shfl_xor(Sq, msk, 64); }
  const float cK = EPSF * Sk + EPSF;
  const float cQ = EPSF * Sq + EPSF;
  float aq0 = 0, aq1 = 0, aq2 = 0, aq3 = 0, ak0 = 0, ak1 = 0, ak2 = 0, ak3 = 0;
  const int nbase = sp << 9;
  for (int it = 0; it < 32; ++it) {
    const int n = nbase + (it << 4) + grp;
    const uint64_t lq = *(const uint64_t*)(qb + ((size_t)n << 6) + (j << 2));
    const uint64_t lk = *(const uint64_t*)(kb + ((size_t)n << 6) + (j << 2));
    const float q0 = us2f((u16)lq), q1 = us2f((u16)(lq >> 16)), q2 = us2f((u16)(lq >> 32)), q3 = us2f((u16)(lq >> 48));
    const float k0 = us2f((u16)lk), k1 = us2f((u16)(lk >> 16)), k2 = us2f((u16)(lk >> 32)), k3 = us2f((u16)(lk >> 48));
    float dq = q0 * ke[0] + q1 * ke[1] + q2 * ke[2] + q3 * ke[3];
    float dk = k0 * qe[0] + k1 * qe[1] + k2 * qe[2] + k3 * qe[3];
#pragma unroll
    for (int msk = 1; msk < 16; msk <<= 1) { dq += __shfl_xor(dq, msk, 64); dk += __shfl_xor(dk, msk, 64); }
    const float si = 1.f / (dq + cK);
    const float so = 1.f / (dk + cQ);
    if (j == 0) si_out[(bh << 12) + n] = si;
    aq0 += q0 * si; aq1 += q1 * si; aq2 += q2 * si; aq3 += q3 * si;
    ak0 += k0 * so; ak1 += k1 * so; ak2 += k2 * so; ak3 += k3 * so;
  }
  __shared__ float redq[16][64];
  __shared__ float redk[16][64];
  redq[grp][(j << 2) + 0] = aq0; redq[grp][(j << 2) + 1] = aq1;
  redq[grp][(j << 2) + 2] = aq2; redq[grp][(j << 2) + 3] = aq3;
  redk[grp][(j << 2) + 0] = ak0; redk[grp][(j << 2) + 1] = ak1;
  redk[grp][(j << 2) + 2] = ak2; redk[grp][(j << 2) + 3] = ak3;
  __syncthreads();
  if (threadIdx.x < 64) {
    float s1 = 0.f, s2 = 0.f;
#pragma unroll
    for (int g = 0; g < 16; ++g) { s1 += redq[g][threadIdx.x]; s2 += redk[g][threadIdx.x]; }
    atomicAdd(&qsi[(bh << 6) + threadIdx.x], s1);
    atomicAdd(&kso[(bh << 6) + threadIdx.x], s2);
  }
}

// ---------------- conserved sink/source -> m = si*sigmoid(cs); e = exp(clip(csrc)); sumexp ----------------
__global__ __launch_bounds__(256) void k_flow2(
    const u16* __restrict__ q, const u16* __restrict__ k,
    const float* __restrict__ qsi, const float* __restrict__ kso,
    const float* __restrict__ si_in,
    float* __restrict__ mo, float* __restrict__ eo, float* __restrict__ sumexp)
{
  const int bh = blockIdx.x >> 3, sp = blockIdx.x & 7;
  const int lane = threadIdx.x & 63, wid = threadIdx.x >> 6;
  const int j = lane & 15;
  const int grp = (wid << 2) | (lane >> 4);
  const u16* qb = q + ((size_t)bh << 18);
  const u16* kb = k + ((size_t)bh << 18);
  float soe[4], qie[4];
#pragma unroll
  for (int t = 0; t < 4; ++t) {
    soe[t] = kso[(bh << 6) + (j << 2) + t] + EPSF;
    qie[t] = qsi[(bh << 6) + (j << 2) + t] + EPSF;
  }
  float Ss = soe[0] + soe[1] + soe[2] + soe[3];
  float Si = qie[0] + qie[1] + qie[2] + qie[3];
#pragma unroll
  for (int msk = 1; msk < 16; msk <<= 1) { Ss += __shfl_xor(Ss, msk, 64); Si += __shfl_xor(Si, msk, 64); }
  const float cS = EPSF * Ss + EPSF;
  const float cR = EPSF * Si + EPSF;
  float esum = 0.f;
  const int nbase = sp << 9;
  for (int it = 0; it < 32; ++it) {
    const int n = nbase + (it << 4) + grp;
    const uint64_t lq = *(const uint64_t*)(qb + ((size_t)n << 6) + (j << 2));
    const uint64_t lk = *(const uint64_t*)(kb + ((size_t)n << 6) + (j << 2));
    const float q0 = us2f((u16)lq), q1 = us2f((u16)(lq >> 16)), q2 = us2f((u16)(lq >> 32)), q3 = us2f((u16)(lq >> 48));
    const float k0 = us2f((u16)lk), k1 = us2f((u16)(lk >> 16)), k2 = us2f((u16)(lk >> 32)), k3 = us2f((u16)(lk >> 48));
    float cs = q0 * soe[0] + q1 * soe[1] + q2 * soe[2] + q3 * soe[3];
    float cr = k0 * qie[0] + k1 * qie[1] + k2 * qie[2] + k3 * qie[3];
#pragma unroll
    for (int msk = 1; msk < 16; msk <<= 1) { cs += __shfl_xor(cs, msk, 64); cr += __shfl_xor(cr, msk, 64); }
    cs += cS;
    cr += cR;
    cr = fminf(1.f, fmaxf(-1.f, cr));
    const float ev = __expf(cr);
    if (j == 0) {
      const float sa = sigm(cs);
      mo[(bh << 12) + n] = si_in[(bh << 12) + n] * sa;
      eo[(bh << 12) + n] = ev;
      esum += ev;
    }
  }
  __shared__ float red[16];
  if (j == 0) red[grp] = esum;
  __syncthreads();
  if (threadIdx.x == 0) {
    float s = 0.f;
#pragma unroll
    for (int g = 0; g < 16; ++g) s += red[g];
    atomicAdd(&sumexp[bh], s);
  }
}

// ---------------- kv via MFMA: kvm[d][e] = sum_n (k[n,d]*e[n]) * v[n,e] ----------------
__global__ __launch_bounds__(256) void k_kv(
    const u16* __restrict__ k, const u16* __restrict__ v,
    const float* __restrict__ e_arr, float* __restrict__ kvm)
{
  __shared__ __align__(16) u16 smem[2 * 64 * 136];  // 34816 B; reused as f32 reduce buf
  u16* kT = smem;
  u16* vT = smem + 64 * 136;
  const int tid = threadIdx.x;
  const int bh = blockIdx.x >> 3, sp = blockIdx.x & 7;
  const int lane = tid & 63, wid = tid >> 6;
  const int r16 = lane & 15, g = lane >> 4;
  const u16* kb = k + ((size_t)bh << 18);
  const u16* vb = v + ((size_t)bh << 18);
  const float* eb = e_arr + ((size_t)bh << 12);

  f32x4 acc[4][4];
#pragma unroll
  for (int i = 0; i < 4; ++i)
#pragma unroll
    for (int j = 0; j < 4; ++j) acc[i][j] = (f32x4){0.f, 0.f, 0.f, 0.f};

  const int nf = (wid << 5) + (g << 3);  // wave n-window + lane-group k offset

  for (int st = 0; st < 4; ++st) {
    const int nst = (sp << 9) + (st << 7);
#pragma unroll
    for (int i = 0; i < 4; ++i) {
      const int c = tid + (i << 8);
      const int nl = c >> 3;              // 0..127
      const int d0 = (c & 7) << 3;        // 0..56
      const int ng = nst + nl;
      short8 k8 = *(const short8*)(kb + ((size_t)ng << 6) + d0);
      short8 v8 = *(const short8*)(vb + ((size_t)ng << 6) + d0);
      const float en = eb[ng];
      const int col = nl ^ (d0 & 56);     // XOR key ((d0>>3)&7)<<3 == d0&56
#pragma unroll
      for (int u = 0; u < 8; ++u) {
        kT[(d0 + u) * 136 + col] = f2bfu(us2f((u16)k8[u]) * en);
        vT[(d0 + u) * 136 + col] = (u16)(unsigned short)v8[u];
      }
    }
    __syncthreads();

    short8 af[4], bf[4];
#pragma unroll
    for (int mi = 0; mi < 4; ++mi) {
      const int row = (mi << 4) + r16;
      af[mi] = *(const short8*)&kT[row * 136 + (nf ^ (row & 56))];
    }
#pragma unroll
    for (int nj = 0; nj < 4; ++nj) {
      const int row = (nj << 4) + r16;
      bf[nj] = *(const short8*)&vT[row * 136 + (nf ^ (row & 56))];
    }
#pragma unroll
    for (int mi = 0; mi < 4; ++mi)
#pragma unroll
      for (int nj = 0; nj < 4; ++nj)
        acc[mi][nj] = __builtin_amdgcn_mfma_f32_16x16x32_bf16(af[mi], bf[nj], acc[mi][nj], 0, 0, 0);
    __syncthreads();
  }

  // cross-wave reduce (two 32-d halves through LDS) + coalesced atomics
  float* red = (float*)smem;
  float* kvb = kvm + ((size_t)bh << 12);
#pragma unroll
  for (int half = 0; half < 2; ++half) {
#pragma unroll
    for (int m2 = 0; m2 < 2; ++m2) {
      const int mi = (half << 1) + m2;
#pragma unroll
      for (int nj = 0; nj < 4; ++nj)
#pragma unroll
        for (int rg = 0; rg < 4; ++rg)
          red[(wid << 11) + (((m2 << 4) + (g << 2) + rg) << 6) + (nj << 4) + r16] = acc[mi][nj][rg];
    }
    __syncthreads();
    const int base = tid << 3;
#pragma unroll
    for (int u2 = 0; u2 < 2; ++u2) {
      const int o = base + (u2 << 2);
      float4 s0 = *(const float4*)&red[o];
      float4 s1 = *(const float4*)&red[2048 + o];
      float4 s2 = *(const float4*)&red[4096 + o];
      float4 s3 = *(const float4*)&red[6144 + o];
      s0.x += s1.x + s2.x + s3.x;
      s0.y += s1.y + s2.y + s3.y;
      s0.z += s1.z + s2.z + s3.z;
      s0.w += s1.w + s2.w + s3.w;
      const int gi = (half << 11) + o;
      atomicAdd(&kvb[gi + 0], s0.x);
      atomicAdd(&kvb[gi + 1], s0.y);
      atomicAdd(&kvb[gi + 2], s0.z);
      atomicAdd(&kvb[gi + 3], s0.w);
    }
    __syncthreads();
  }
}

// ---------------- x_update = (q @ kv) * m[n] * scale -> attn [B][N][C] bf16 (MFMA) ----------------
__global__ __launch_bounds__(256) void k_xup(
    const u16* __restrict__ q, const float* __restrict__ kvm,
    const float* __restrict__ m_arr, const float* __restrict__ sumexp,
    u16* __restrict__ attn)
{
  const int bh = blockIdx.y;
  const int n0 = blockIdx.x << 7;
  const int b = bh / 12, h = bh % 12;
  __shared__ __align__(16) u16 qs[128 * 72];   // stride 72 elems (144B): 2-way banks, 16B aligned
  __shared__ __align__(16) u16 kvs[64 * 72];   // kv^T as [e][d] bf16
  const int tid = threadIdx.x, lane = tid & 63, wid = tid >> 6;
  const u16* qg = q + ((size_t)bh << 18) + ((size_t)n0 << 6);
#pragma unroll
  for (int i = 0; i < 4; ++i) {
    const int c = tid + (i << 8);
    const int nl = c >> 3, d0 = (c & 7) << 3;
    *(short8*)&qs[nl * 72 + d0] = *(const short8*)(qg + (nl << 6) + d0);
  }
  const float* kvg = kvm + ((size_t)bh << 12);
#pragma unroll
  for (int i = 0; i < 4; ++i) {
    const int idx = (tid << 2) + (i << 10);
    const int d = idx >> 6, e0 = idx & 63;
    float4 vv = *(const float4*)(kvg + idx);
    kvs[(e0 + 0) * 72 + d] = f2bfu(vv.x);
    kvs[(e0 + 1) * 72 + d] = f2bfu(vv.y);
    kvs[(e0 + 2) * 72 + d] = f2bfu(vv.z);
    kvs[(e0 + 3) * 72 + d] = f2bfu(vv.w);
  }
  __syncthreads();
  const float scale = 4096.f / sumexp[bh];
  const int r16 = lane & 15, kg8 = (lane >> 4) << 3;
  f32x4 acc[2][4];
#pragma unroll
  for (int i = 0; i < 2; ++i)
#pragma unroll
    for (int j = 0; j < 4; ++j) acc[i][j] = (f32x4){0.f, 0.f, 0.f, 0.f};
#pragma unroll
  for (int kk = 0; kk < 2; ++kk) {
    short8 af[2], bfv[4];
#pragma unroll
    for (int mi = 0; mi < 2; ++mi)
      af[mi] = *(const short8*)&qs[((wid << 5) + (mi << 4) + r16) * 72 + (kk << 5) + kg8];
#pragma unroll
    for (int nj = 0; nj < 4; ++nj)
      bfv[nj] = *(const short8*)&kvs[((nj << 4) + r16) * 72 + (kk << 5) + kg8];
#pragma unroll
    for (int mi = 0; mi < 2; ++mi)
#pragma unroll
      for (int nj = 0; nj < 4; ++nj)
        acc[mi][nj] = __builtin_amdgcn_mfma_f32_16x16x32_bf16(af[mi], bfv[nj], acc[mi][nj], 0, 0, 0);
  }
#pragma unroll
  for (int mi = 0; mi < 2; ++mi) {
#pragma unroll
    for (int rg = 0; rg < 4; ++rg) {
      const int n = n0 + (wid << 5) + (mi << 4) + ((lane >> 4) << 2) + rg;
      const float mult = m_arr[((size_t)bh << 12) + n] * scale;
#pragma unroll
      for (int nj = 0; nj < 4; ++nj) {
        const int e = (nj << 4) + r16;
        attn[((size_t)(b * 4096 + n)) * 768 + (h << 6) + e] = f2bfu(acc[mi][nj][rg] * mult);
      }
    }
  }
}

extern "C" void kernel_launch(void* const* d_in, const int* in_sizes, int n_in,
                              void* d_out, int out_size, void* d_ws, size_t ws_size,
                              hipStream_t stream)
{
  (void)in_sizes; (void)n_in; (void)out_size; (void)ws_size;
  const float* x     = (const float*)d_in[0];
  const float* Wqkv  = (const float*)d_in[1];
  const float* bqkv  = (const float*)d_in[2];
  const float* Wproj = (const float*)d_in[3];
  const float* bproj = (const float*)d_in[4];
  float* out = (float*)d_out;

  char* ws = (char*)d_ws;
  size_t off = 0;
  auto alloc = [&](size_t bytes) -> char* {
    char* p = ws + off;
    off += (bytes + 255) & ~(size_t)255;
    return p;
  };
  u16* q    = (u16*)alloc(50331648);       // [B,H,N,D] bf16
  u16* k    = (u16*)alloc(50331648);
  u16* v    = (u16*)alloc(50331648);
  u16* xbf  = (u16*)alloc(50331648);       // x bf16; reused as attn output
  u16* WqT  = (u16*)alloc(3538944);        // [2304][768] bf16
  u16* WpT  = (u16*)alloc(1179648);        // [768][768] bf16
  float* si = (float*)alloc(1572864);      // [B*H][N]
  float* mb = (float*)alloc(1572864);      // si * sink_allocation
  float* eb = (float*)alloc(1572864);      // exp(clipped conserved_source)
  char* zbase = ws + off;
  float* qsum   = (float*)alloc(24576);
  float* ksum   = (float*)alloc(24576);
  float* qsi    = (float*)alloc(24576);
  float* kso    = (float*)alloc(24576);
  float* sumexp = (float*)alloc(512);
  float* kvm    = (float*)alloc(1572864);  // [B*H][64 d][64 e] f32
  const size_t zbytes = (size_t)((ws + off) - zbase);

  hipMemsetAsync(zbase, 0, zbytes, stream);
  k_cvt_x<<<24576, 256, 0, stream>>>(x, xbf);
  k_transpose<<<dim3(72, 24), 256, 0, stream>>>(Wqkv, WqT, 768, 2304);
  k_transpose<<<dim3(24, 24), 256, 0, stream>>>(Wproj, WpT, 768, 768);
  k_gemm<0><<<dim3(18, 256), 256, 0, stream>>>(xbf, WqT, bqkv, q, k, v, nullptr);
  k_sums<<<768, 256, 0, stream>>>(q, k, qsum, ksum);
  k_flow1<<<768, 256, 0, stream>>>(q, k, qsum, ksum, si, qsi, kso);
  k_flow2<<<768, 256, 0, stream>>>(q, k, qsi, kso, si, mb, eb, sumexp);
  k_kv<<<768, 256, 0, stream>>>(k, v, eb, kvm);
  k_xup<<<dim3(32, 96), 256, 0, stream>>>(q, kvm, mb, sumexp, xbf);
  k_gemm<1><<<dim3(6, 256), 256, 0, stream>>>(xbf, WpT, bproj, nullptr, nullptr, nullptr, out);
}

// Round 6
// 443.428 us; speedup vs baseline: 1.1822x; 1.0765x over previous
//
#include <hip/hip_runtime.h>
#include <stdint.h>

#define EPSF 1e-6f

typedef unsigned short u16;
typedef __attribute__((ext_vector_type(8))) short short8;
typedef __attribute__((ext_vector_type(4))) float f32x4;

__device__ __forceinline__ float us2f(u16 u) {
  union { float f; unsigned int i; } c; c.i = ((unsigned int)u) << 16; return c.f;
}
__device__ __forceinline__ u16 f2bfu(float f) {
  union { float f; unsigned int i; } c; c.f = f;
  unsigned int i = c.i;
  return (u16)((i + 0x7FFFu + ((i >> 16) & 1u)) >> 16);
}
__device__ __forceinline__ float sigm(float x) { return 1.f / (1.f + __expf(-x)); }

typedef __attribute__((address_space(3))) unsigned int lds_u32;
typedef const __attribute__((address_space(1))) unsigned int glb_u32;
__device__ __forceinline__ void gl_lds16(const u16* g, u16* l) {
  __builtin_amdgcn_global_load_lds((glb_u32*)g, (lds_u32*)l, 16, 0, 0);
}

// ---------------- convert x (f32 -> bf16), 4 elems/thread ----------------
__global__ void k_cvt_x(const float* __restrict__ in, u16* __restrict__ out) {
  const int i = blockIdx.x * 256 + threadIdx.x;
  float4 v = ((const float4*)in)[i];
  ushort4 o;
  o.x = f2bfu(v.x); o.y = f2bfu(v.y); o.z = f2bfu(v.z); o.w = f2bfu(v.w);
  ((ushort4*)out)[i] = o;
}

// ---------------- transpose + convert: in f32 [R][C] -> out bf16 [C][R] ----------------
__global__ void k_transpose(const float* __restrict__ in, u16* __restrict__ out, int R, int C) {
  __shared__ float tile[32][33];
  const int tx = threadIdx.x & 31, ty = threadIdx.x >> 5;  // 32x8
  const int c0 = blockIdx.x << 5, r0 = blockIdx.y << 5;
  for (int i = ty; i < 32; i += 8) tile[i][tx] = in[(size_t)(r0 + i) * C + c0 + tx];
  __syncthreads();
  for (int i = ty; i < 32; i += 8) out[(size_t)(c0 + i) * R + r0 + tx] = f2bfu(tile[tx][i]);
}

// ---------------- GEMM: A[M][768] bf16 x BT[NC][768] bf16, 128x128 tile, BK=32 ----------------
// Proven round-3/5 structure (2-buffer, vmcnt(0)+barrier, XOR swizzle).
// MODE 0: flat qkv store (sigmoid on q/k cols) + fused qsum/ksum partial sums.
// MODE 1: proj epilogue (f32 sigmoid(2x) store).
template <int MODE>
__global__ __launch_bounds__(256) void k_gemm(
    const u16* __restrict__ A, const u16* __restrict__ BT,
    const float* __restrict__ bias,
    u16* __restrict__ qkvo, float* __restrict__ qsum, float* __restrict__ ksum,
    float* __restrict__ outf)
{
  __shared__ __align__(16) u16 sA[2][128 * 32];
  __shared__ __align__(16) u16 sB[2][128 * 32];
  const int tid = threadIdx.x;
  const int lane = tid & 63;
  const int wid = tid >> 6;
  const int wr = wid >> 1, wc = wid & 1;
  // bijective XCD swizzle (nwg % 8 == 0 for both grids)
  const int nx = gridDim.x;
  int lid = blockIdx.y * nx + blockIdx.x;
  const int q8 = (nx * gridDim.y) >> 3;
  lid = (lid & 7) * q8 + (lid >> 3);
  const int m0 = (lid / nx) << 7;
  const int n0 = (lid % nx) << 7;
  const int srow = lane >> 2;                              // 0..15 (row within 16-row chunk)
  const int cgsw = ((lane & 3) ^ ((lane >> 3) & 3)) << 3;  // pre-swizzled col-group (elems)

  const u16* ga0 = A  + (size_t)(m0 + (wid << 4) + srow) * 768 + cgsw;
  const u16* ga1 = A  + (size_t)(m0 + ((wid + 4) << 4) + srow) * 768 + cgsw;
  const u16* gb0 = BT + (size_t)(n0 + (wid << 4) + srow) * 768 + cgsw;
  const u16* gb1 = BT + (size_t)(n0 + ((wid + 4) << 4) + srow) * 768 + cgsw;

  f32x4 acc[4][4];
#pragma unroll
  for (int i = 0; i < 4; ++i)
#pragma unroll
    for (int j = 0; j < 4; ++j) acc[i][j] = (f32x4){0.f, 0.f, 0.f, 0.f};

#define STAGE(buf, ktel)                                        \
  do {                                                          \
    gl_lds16(ga0 + (ktel), &sA[buf][(wid) * 512]);              \
    gl_lds16(ga1 + (ktel), &sA[buf][(wid + 4) * 512]);          \
    gl_lds16(gb0 + (ktel), &sB[buf][(wid) * 512]);              \
    gl_lds16(gb1 + (ktel), &sB[buf][(wid + 4) * 512]);          \
  } while (0)

  STAGE(0, 0);
  asm volatile("s_waitcnt vmcnt(0)" ::: "memory");
  __syncthreads();

  const int r16 = lane & 15;
  // read-side swizzled k-slot: slot = (lane>>4) ^ ((row>>1)&3), row%16 == r16
  const int ksw = (((lane >> 4) ^ ((r16 >> 1) & 3)) << 3);
  int cur = 0;
  for (int kt = 1; kt <= 24; ++kt) {
    if (kt < 24) {
      if (cur) STAGE(0, kt * 32); else STAGE(1, kt * 32);
    }
    const u16* pa = &sA[cur][0];
    const u16* pb = &sB[cur][0];
    short8 af[4], bfv[4];
#pragma unroll
    for (int i = 0; i < 4; ++i)
      af[i] = *(const short8*)(pa + ((wr << 6) + (i << 4) + r16) * 32 + ksw);
#pragma unroll
    for (int j = 0; j < 4; ++j)
      bfv[j] = *(const short8*)(pb + ((wc << 6) + (j << 4) + r16) * 32 + ksw);
#pragma unroll
    for (int i = 0; i < 4; ++i)
#pragma unroll
      for (int j = 0; j < 4; ++j)
        acc[i][j] = __builtin_amdgcn_mfma_f32_16x16x32_bf16(af[i], bfv[j], acc[i][j], 0, 0, 0);
    asm volatile("s_waitcnt vmcnt(0)" ::: "memory");
    __syncthreads();
    cur ^= 1;
  }
#undef STAGE

  if (MODE == 0) {
    const int colc = n0 + (wc << 6);        // wave's 64-col window base
    const bool sg = (colc < 1536);          // uniform: q/k (sigmoid+sum) vs v
    float jsum[4] = {0.f, 0.f, 0.f, 0.f};
#pragma unroll
    for (int i = 0; i < 4; ++i) {
      const int rowb = m0 + (wr << 6) + (i << 4) + ((lane >> 4) << 2);
#pragma unroll
      for (int j = 0; j < 4; ++j) {
        const int col = colc + (j << 4) + r16;
        const float bcol = bias[col];
        if (sg) {
#pragma unroll
          for (int rg = 0; rg < 4; ++rg) {
            const float val = sigm(acc[i][j][rg] + bcol);
            jsum[j] += val;
            qkvo[(size_t)(rowb + rg) * 2304 + col] = f2bfu(val);
          }
        } else {
#pragma unroll
          for (int rg = 0; rg < 4; ++rg)
            qkvo[(size_t)(rowb + rg) * 2304 + col] = f2bfu(acc[i][j][rg] + bcol);
        }
      }
    }
    if (sg) {
      // reduce over the 4 row-subgroups, then one atomic per (lane<16, j)
#pragma unroll
      for (int j = 0; j < 4; ++j) {
        jsum[j] += __shfl_xor(jsum[j], 16, 64);
        jsum[j] += __shfl_xor(jsum[j], 32, 64);
      }
      if (lane < 16) {
        const int b12 = (m0 >> 12) * 12;
        float* sdst = (colc >= 768) ? ksum : qsum;
        const int cb = (colc >= 768) ? colc - 768 : colc;  // 0..767 = h*64+d
#pragma unroll
        for (int j = 0; j < 4; ++j)
          atomicAdd(&sdst[(b12 << 6) + cb + (j << 4) + r16], jsum[j]);
      }
    }
  } else {
#pragma unroll
    for (int i = 0; i < 4; ++i) {
      const int rowb = m0 + (wr << 6) + (i << 4) + ((lane >> 4) << 2);
#pragma unroll
      for (int j = 0; j < 4; ++j) {
        const int col = n0 + (wc << 6) + (j << 4) + r16;
        const float bcol = bias[col];
#pragma unroll
        for (int rg = 0; rg < 4; ++rg)
          outf[(size_t)(rowb + rg) * 768 + col] = sigm(2.f * (acc[i][j][rg] + bcol));
      }
    }
  }
}

// ---------------- si/so + qsi/kso (flat qkv layout) ----------------
__global__ __launch_bounds__(256) void k_flow1(
    const u16* __restrict__ qkv,
    const float* __restrict__ qsum, const float* __restrict__ ksum,
    float* __restrict__ si_out, float* __restrict__ qsi, float* __restrict__ kso)
{
  const int bh = blockIdx.x >> 3, sp = blockIdx.x & 7;
  const int lane = threadIdx.x & 63, wid = threadIdx.x >> 6;
  const int j = lane & 15;
  const int grp = (wid << 2) | (lane >> 4);
  const u16* base = qkv + (size_t)(bh / 12) * 4096 * 2304 + (bh % 12) * 64;
  float ke[4], qe[4];
#pragma unroll
  for (int t = 0; t < 4; ++t) {
    ke[t] = ksum[(bh << 6) + (j << 2) + t] + EPSF;
    qe[t] = qsum[(bh << 6) + (j << 2) + t] + EPSF;
  }
  float Sk = ke[0] + ke[1] + ke[2] + ke[3];
  float Sq = qe[0] + qe[1] + qe[2] + qe[3];
#pragma unroll
  for (int msk = 1; msk < 16; msk <<= 1) { Sk += __shfl_xor(Sk, msk, 64); Sq += __shfl_xor(Sq, msk, 64); }
  const float cK = EPSF * Sk + EPSF;
  const float cQ = EPSF * Sq + EPSF;
  float aq0 = 0, aq1 = 0, aq2 = 0, aq3 = 0, ak0 = 0, ak1 = 0, ak2 = 0, ak3 = 0;
  const int nbase = sp << 9;
  for (int it = 0; it < 32; ++it) {
    const int n = nbase + (it << 4) + grp;
    const size_t ro = (size_t)n * 2304 + (j << 2);
    const uint64_t lq = *(const uint64_t*)(base + ro);
    const uint64_t lk = *(const uint64_t*)(base + ro + 768);
    const float q0 = us2f((u16)lq), q1 = us2f((u16)(lq >> 16)), q2 = us2f((u16)(lq >> 32)), q3 = us2f((u16)(lq >> 48));
    const float k0 = us2f((u16)lk), k1 = us2f((u16)(lk >> 16)), k2 = us2f((u16)(lk >> 32)), k3 = us2f((u16)(lk >> 48));
    float dq = q0 * ke[0] + q1 * ke[1] + q2 * ke[2] + q3 * ke[3];
    float dk = k0 * qe[0] + k1 * qe[1] + k2 * qe[2] + k3 * qe[3];
#pragma unroll
    for (int msk = 1; msk < 16; msk <<= 1) { dq += __shfl_xor(dq, msk, 64); dk += __shfl_xor(dk, msk, 64); }
    const float si = 1.f / (dq + cK);
    const float so = 1.f / (dk + cQ);
    if (j == 0) si_out[(bh << 12) + n] = si;
    aq0 += q0 * si; aq1 += q1 * si; aq2 += q2 * si; aq3 += q3 * si;
    ak0 += k0 * so; ak1 += k1 * so; ak2 += k2 * so; ak3 += k3 * so;
  }
  __shared__ float redq[16][64];
  __shared__ float redk[16][64];
  redq[grp][(j << 2) + 0] = aq0; redq[grp][(j << 2) + 1] = aq1;
  redq[grp][(j << 2) + 2] = aq2; redq[grp][(j << 2) + 3] = aq3;
  redk[grp][(j << 2) + 0] = ak0; redk[grp][(j << 2) + 1] = ak1;
  redk[grp][(j << 2) + 2] = ak2; redk[grp][(j << 2) + 3] = ak3;
  __syncthreads();
  if (threadIdx.x < 64) {
    float s1 = 0.f, s2 = 0.f;
#pragma unroll
    for (int g = 0; g < 16; ++g) { s1 += redq[g][threadIdx.x]; s2 += redk[g][threadIdx.x]; }
    atomicAdd(&qsi[(bh << 6) + threadIdx.x], s1);
    atomicAdd(&kso[(bh << 6) + threadIdx.x], s2);
  }
}

// ---------------- fused flow2 + kv (MFMA): e/m/sumexp inline, kvm[d][e] accumulate ----------------
__global__ __launch_bounds__(256) void k_fkv(
    const u16* __restrict__ qkv,
    const float* __restrict__ qsi, const float* __restrict__ kso,
    const float* __restrict__ si_in,
    float* __restrict__ mo, float* __restrict__ sumexp, float* __restrict__ kvm)
{
  __shared__ __align__(16) u16 smem[2 * 64 * 136];  // 34816 B; reused as f32 reduce buf
  u16* kT = smem;
  u16* vT = smem + 64 * 136;
  const int tid = threadIdx.x;
  const int bh = blockIdx.x >> 3, sp = blockIdx.x & 7;
  const int lane = tid & 63, wid = tid >> 6;
  const int r16 = lane & 15, g = lane >> 4;
  const u16* base = qkv + (size_t)(bh / 12) * 4096 * 2304 + (bh % 12) * 64;
  const float* sib = si_in + ((size_t)bh << 12);
  float* mob = mo + ((size_t)bh << 12);

  // per-thread d-slice (constant across stages/iters)
  const int d0 = (tid & 7) << 3;
  float qie[8], soe[8];
#pragma unroll
  for (int u = 0; u < 8; ++u) {
    qie[u] = qsi[(bh << 6) + d0 + u] + EPSF;
    soe[u] = kso[(bh << 6) + d0 + u] + EPSF;
  }
  // block-uniform eps terms: cR = eps*sum(qsi+eps)+eps, cS = eps*sum(kso+eps)+eps
  float Sq = qsi[(bh << 6) + lane] + EPSF;
  float Sk = kso[(bh << 6) + lane] + EPSF;
#pragma unroll
  for (int m = 1; m < 64; m <<= 1) { Sq += __shfl_xor(Sq, m, 64); Sk += __shfl_xor(Sk, m, 64); }
  const float cR = EPSF * Sq + EPSF;
  const float cS = EPSF * Sk + EPSF;

  f32x4 acc[4][4];
#pragma unroll
  for (int i = 0; i < 4; ++i)
#pragma unroll
    for (int j = 0; j < 4; ++j) acc[i][j] = (f32x4){0.f, 0.f, 0.f, 0.f};

  const int nf = (wid << 5) + (g << 3);  // wave n-window + lane-group k offset
  float esum = 0.f;

  for (int st = 0; st < 4; ++st) {
    const int nst = (sp << 9) + (st << 7);
#pragma unroll
    for (int i = 0; i < 4; ++i) {
      const int c = tid + (i << 8);
      const int nl = c >> 3;              // 0..127
      const int ng = nst + nl;
      const u16* rp = base + (size_t)ng * 2304 + d0;
      short8 q8 = *(const short8*)(rp);
      short8 k8 = *(const short8*)(rp + 768);
      short8 v8 = *(const short8*)(rp + 1536);
      float pcs = 0.f, pcr = 0.f;
#pragma unroll
      for (int u = 0; u < 8; ++u) {
        pcs += us2f((u16)q8[u]) * soe[u];
        pcr += us2f((u16)k8[u]) * qie[u];
      }
#pragma unroll
      for (int m = 1; m < 8; m <<= 1) { pcs += __shfl_xor(pcs, m, 64); pcr += __shfl_xor(pcr, m, 64); }
      float cr = pcr + cR;
      cr = fminf(1.f, fmaxf(-1.f, cr));
      const float ev = __expf(cr);
      const int col = nl ^ (d0 & 56);     // write-side XOR swizzle (proven, round 3)
#pragma unroll
      for (int u = 0; u < 8; ++u) {
        kT[(d0 + u) * 136 + col] = f2bfu(us2f((u16)k8[u]) * ev);
        vT[(d0 + u) * 136 + col] = (u16)(unsigned short)v8[u];
      }
      if ((tid & 7) == 0) {
        mob[ng] = sib[ng] * sigm(pcs + cS);
        esum += ev;
      }
    }
    __syncthreads();

    short8 af[4], bf[4];
#pragma unroll
    for (int mi = 0; mi < 4; ++mi) {
      const int row = (mi << 4) + r16;
      af[mi] = *(const short8*)&kT[row * 136 + (nf ^ (row & 56))];
    }
#pragma unroll
    for (int nj = 0; nj < 4; ++nj) {
      const int row = (nj << 4) + r16;
      bf[nj] = *(const short8*)&vT[row * 136 + (nf ^ (row & 56))];
    }
#pragma unroll
    for (int mi = 0; mi < 4; ++mi)
#pragma unroll
      for (int nj = 0; nj < 4; ++nj)
        acc[mi][nj] = __builtin_amdgcn_mfma_f32_16x16x32_bf16(af[mi], bf[nj], acc[mi][nj], 0, 0, 0);
    __syncthreads();
  }

  // cross-wave reduce (two 32-d halves through LDS) + coalesced atomics
  float* red = (float*)smem;
  float* kvb = kvm + ((size_t)bh << 12);
#pragma unroll
  for (int half = 0; half < 2; ++half) {
#pragma unroll
    for (int m2 = 0; m2 < 2; ++m2) {
      const int mi = (half << 1) + m2;
#pragma unroll
      for (int nj = 0; nj < 4; ++nj)
#pragma unroll
        for (int rg = 0; rg < 4; ++rg)
          red[(wid << 11) + (((m2 << 4) + (g << 2) + rg) << 6) + (nj << 4) + r16] = acc[mi][nj][rg];
    }
    __syncthreads();
    const int base2 = tid << 3;
#pragma unroll
    for (int u2 = 0; u2 < 2; ++u2) {
      const int o = base2 + (u2 << 2);
      float4 s0 = *(const float4*)&red[o];
      float4 s1 = *(const float4*)&red[2048 + o];
      float4 s2 = *(const float4*)&red[4096 + o];
      float4 s3 = *(const float4*)&red[6144 + o];
      s0.x += s1.x + s2.x + s3.x;
      s0.y += s1.y + s2.y + s3.y;
      s0.z += s1.z + s2.z + s3.z;
      s0.w += s1.w + s2.w + s3.w;
      const int gi = (half << 11) + o;
      atomicAdd(&kvb[gi + 0], s0.x);
      atomicAdd(&kvb[gi + 1], s0.y);
      atomicAdd(&kvb[gi + 2], s0.z);
      atomicAdd(&kvb[gi + 3], s0.w);
    }
    __syncthreads();
  }

  // sumexp: lanes 0,8,...,56 hold partials; fold within wave, 1 atomic/wave
  esum += __shfl_xor(esum, 8, 64);
  esum += __shfl_xor(esum, 16, 64);
  esum += __shfl_xor(esum, 32, 64);
  if (lane == 0) atomicAdd(&sumexp[bh], esum);
}

// ---------------- x_update = (q @ kv) * m[n] * scale -> attn [B][N][C] bf16 (MFMA) ----------------
__global__ __launch_bounds__(256) void k_xup(
    const u16* __restrict__ qkv, const float* __restrict__ kvm,
    const float* __restrict__ m_arr, const float* __restrict__ sumexp,
    u16* __restrict__ attn)
{
  const int bh = blockIdx.y;
  const int n0 = blockIdx.x << 7;
  const int b = bh / 12, h = bh % 12;
  __shared__ __align__(16) u16 qs[128 * 72];   // stride 72 elems (144B): 2-way banks, 16B aligned
  __shared__ __align__(16) u16 kvs[64 * 72];   // kv^T as [e][d] bf16
  const int tid = threadIdx.x, lane = tid & 63, wid = tid >> 6;
  const u16* qg = qkv + (size_t)b * 4096 * 2304 + (size_t)n0 * 2304 + h * 64;
#pragma unroll
  for (int i = 0; i < 4; ++i) {
    const int c = tid + (i << 8);
    const int nl = c >> 3, d0 = (c & 7) << 3;
    *(short8*)&qs[nl * 72 + d0] = *(const short8*)(qg + (size_t)nl * 2304 + d0);
  }
  const float* kvg = kvm + ((size_t)bh << 12);
#pragma unroll
  for (int i = 0; i < 4; ++i) {
    const int idx = (tid << 2) + (i << 10);
    const int d = idx >> 6, e0 = idx & 63;
    float4 vv = *(const float4*)(kvg + idx);
    kvs[(e0 + 0) * 72 + d] = f2bfu(vv.x);
    kvs[(e0 + 1) * 72 + d] = f2bfu(vv.y);
    kvs[(e0 + 2) * 72 + d] = f2bfu(vv.z);
    kvs[(e0 + 3) * 72 + d] = f2bfu(vv.w);
  }
  __syncthreads();
  const float scale = 4096.f / sumexp[bh];
  const int r16 = lane & 15, kg8 = (lane >> 4) << 3;
  f32x4 acc[2][4];
#pragma unroll
  for (int i = 0; i < 2; ++i)
#pragma unroll
    for (int j = 0; j < 4; ++j) acc[i][j] = (f32x4){0.f, 0.f, 0.f, 0.f};
#pragma unroll
  for (int kk = 0; kk < 2; ++kk) {
    short8 af[2], bfv[4];
#pragma unroll
    for (int mi = 0; mi < 2; ++mi)
      af[mi] = *(const short8*)&qs[((wid << 5) + (mi << 4) + r16) * 72 + (kk << 5) + kg8];
#pragma unroll
    for (int nj = 0; nj < 4; ++nj)
      bfv[nj] = *(const short8*)&kvs[((nj << 4) + r16) * 72 + (kk << 5) + kg8];
#pragma unroll
    for (int mi = 0; mi < 2; ++mi)
#pragma unroll
      for (int nj = 0; nj < 4; ++nj)
        acc[mi][nj] = __builtin_amdgcn_mfma_f32_16x16x32_bf16(af[mi], bfv[nj], acc[mi][nj], 0, 0, 0);
  }
#pragma unroll
  for (int mi = 0; mi < 2; ++mi) {
#pragma unroll
    for (int rg = 0; rg < 4; ++rg) {
      const int n = n0 + (wid << 5) + (mi << 4) + ((lane >> 4) << 2) + rg;
      const float mult = m_arr[((size_t)bh << 12) + n] * scale;
#pragma unroll
      for (int nj = 0; nj < 4; ++nj) {
        const int e = (nj << 4) + r16;
        attn[((size_t)(b * 4096 + n)) * 768 + (h << 6) + e] = f2bfu(acc[mi][nj][rg] * mult);
      }
    }
  }
}

extern "C" void kernel_launch(void* const* d_in, const int* in_sizes, int n_in,
                              void* d_out, int out_size, void* d_ws, size_t ws_size,
                              hipStream_t stream)
{
  (void)in_sizes; (void)n_in; (void)out_size; (void)ws_size;
  const float* x     = (const float*)d_in[0];
  const float* Wqkv  = (const float*)d_in[1];
  const float* bqkv  = (const float*)d_in[2];
  const float* Wproj = (const float*)d_in[3];
  const float* bproj = (const float*)d_in[4];
  float* out = (float*)d_out;

  char* ws = (char*)d_ws;
  size_t off = 0;
  auto alloc = [&](size_t bytes) -> char* {
    char* p = ws + off;
    off += (bytes + 255) & ~(size_t)255;
    return p;
  };
  u16* qkv  = (u16*)alloc(150994944);      // [32768][2304] bf16 flat (q|k|v)
  u16* xbf  = (u16*)alloc(50331648);       // x bf16; reused as attn output
  u16* WqT  = (u16*)alloc(3538944);        // [2304][768] bf16
  u16* WpT  = (u16*)alloc(1179648);        // [768][768] bf16
  float* si = (float*)alloc(1572864);      // [B*H][N]
  float* mb = (float*)alloc(1572864);      // si * sink_allocation
  char* zbase = ws + off;
  float* qsum   = (float*)alloc(24576);
  float* ksum   = (float*)alloc(24576);
  float* qsi    = (float*)alloc(24576);
  float* kso    = (float*)alloc(24576);
  float* sumexp = (float*)alloc(512);
  float* kvm    = (float*)alloc(1572864);  // [B*H][64 d][64 e] f32
  const size_t zbytes = (size_t)((ws + off) - zbase);

  hipMemsetAsync(zbase, 0, zbytes, stream);
  k_cvt_x<<<24576, 256, 0, stream>>>(x, xbf);
  k_transpose<<<dim3(72, 24), 256, 0, stream>>>(Wqkv, WqT, 768, 2304);
  k_transpose<<<dim3(24, 24), 256, 0, stream>>>(Wproj, WpT, 768, 768);
  k_gemm<0><<<dim3(18, 256), 256, 0, stream>>>(xbf, WqT, bqkv, qkv, qsum, ksum, nullptr);
  k_flow1<<<768, 256, 0, stream>>>(qkv, qsum, ksum, si, qsi, kso);
  k_fkv<<<768, 256, 0, stream>>>(qkv, qsi, kso, si, mb, sumexp, kvm);
  k_xup<<<dim3(32, 96), 256, 0, stream>>>(qkv, kvm, mb, sumexp, xbf);
  k_gemm<1><<<dim3(6, 256), 256, 0, stream>>>(xbf, WpT, bproj, nullptr, nullptr, nullptr, out);
}

// Round 7
// 416.810 us; speedup vs baseline: 1.2577x; 1.0639x over previous
//
#include <hip/hip_runtime.h>
#include <stdint.h>

#define EPSF 1e-6f

typedef unsigned short u16;
typedef __attribute__((ext_vector_type(8))) short short8;
typedef __attribute__((ext_vector_type(4))) float f32x4;

__device__ __forceinline__ float us2f(u16 u) {
  union { float f; unsigned int i; } c; c.i = ((unsigned int)u) << 16; return c.f;
}
__device__ __forceinline__ u16 f2bfu(float f) {
  union { float f; unsigned int i; } c; c.f = f;
  unsigned int i = c.i;
  return (u16)((i + 0x7FFFu + ((i >> 16) & 1u)) >> 16);
}
__device__ __forceinline__ float sigm(float x) { return 1.f / (1.f + __expf(-x)); }

typedef __attribute__((address_space(3))) unsigned int lds_u32;
typedef const __attribute__((address_space(1))) unsigned int glb_u32;
__device__ __forceinline__ void gl_lds16(const u16* g, u16* l) {
  __builtin_amdgcn_global_load_lds((glb_u32*)g, (lds_u32*)l, 16, 0, 0);
}

// ---------------- convert x (f32 -> bf16), 4 elems/thread ----------------
__global__ void k_cvt_x(const float* __restrict__ in, u16* __restrict__ out) {
  const int i = blockIdx.x * 256 + threadIdx.x;
  float4 v = ((const float4*)in)[i];
  ushort4 o;
  o.x = f2bfu(v.x); o.y = f2bfu(v.y); o.z = f2bfu(v.z); o.w = f2bfu(v.w);
  ((ushort4*)out)[i] = o;
}

// ---------------- transpose + convert: in f32 [R][C] -> out bf16 [C][R] ----------------
__global__ void k_transpose(const float* __restrict__ in, u16* __restrict__ out, int R, int C) {
  __shared__ float tile[32][33];
  const int tx = threadIdx.x & 31, ty = threadIdx.x >> 5;  // 32x8
  const int c0 = blockIdx.x << 5, r0 = blockIdx.y << 5;
  for (int i = ty; i < 32; i += 8) tile[i][tx] = in[(size_t)(r0 + i) * C + c0 + tx];
  __syncthreads();
  for (int i = ty; i < 32; i += 8) out[(size_t)(c0 + i) * R + r0 + tx] = f2bfu(tile[tx][i]);
}

// ---------------- GEMM: 256x256 tile, 8 waves (512t), BK=32, 4-slot LDS ring ----------------
// Counted vmcnt(8), prefetch distance 3 K-steps, one s_barrier per step (no drain in loop).
// LDS: A slots [s*8192, +8192) elems, B slots at 32768 + s*8192. 128 KB total.
// Chunk swizzle within 64B rows: chunk' = chunk ^ ((row>>1)&3)  (round-5-verified, 0 conflicts);
// applied on the pre-swizzled GLOBAL source (global_load_lds writes linearly) and on reads.
// MODE 0: flat qkv store (sigmoid q/k) + fused qsum/ksum. MODE 1: proj sigmoid(2x) f32 store.
template <int MODE>
__global__ __launch_bounds__(512, 2) void k_gemm(
    const u16* __restrict__ A, const u16* __restrict__ BT,
    const float* __restrict__ bias,
    u16* __restrict__ qkvo, float* __restrict__ qsum, float* __restrict__ ksum,
    float* __restrict__ outf)
{
  __shared__ __align__(16) u16 smem[65536];  // 128 KB
  const int tid = threadIdx.x;
  const int lane = tid & 63;
  const int wid = tid >> 6;           // 0..7
  const int wm = wid >> 2, wn = wid & 3;
  // bijective XCD swizzle (nwg % 8 == 0 for both grids)
  const int nx = gridDim.x;
  int lid = blockIdx.y * nx + blockIdx.x;
  const int q8 = (nx * gridDim.y) >> 3;
  lid = (lid & 7) * q8 + (lid >> 3);
  const int m0 = (lid / nx) << 8;
  const int n0 = (lid % nx) << 8;

  // ---- staging map: thread covers 16B chunks {tid, tid+512} of A-slot and B-slot ----
  const int rowS = tid >> 2;                       // 0..127 (load1: +128, (row>>1)&3 unchanged)
  const int sub  = tid & 3;
  const int subx = sub ^ ((rowS >> 1) & 3);        // pre-swizzled global k-chunk
  const u16* gA = A  + (size_t)(m0 + rowS) * 768 + (subx << 3);
  const u16* gB = BT + (size_t)(n0 + rowS) * 768 + (subx << 3);
  const int dstc = tid << 3;                       // elem offset of chunk tid

  // ---- read map ----
  const int r16 = lane & 15;
  const int sgrp = lane >> 4;                      // k chunk index (8 elems each)
  int offA[8], offB[4];
#pragma unroll
  for (int mi = 0; mi < 8; ++mi) {
    const int ra = (wm << 7) + (mi << 4) + r16;
    offA[mi] = ra * 32 + ((sgrp ^ ((ra >> 1) & 3)) << 3);
  }
#pragma unroll
  for (int nj = 0; nj < 4; ++nj) {
    const int rb = (wn << 6) + (nj << 4) + r16;
    offB[nj] = rb * 32 + ((sgrp ^ ((rb >> 1) & 3)) << 3);
  }

  f32x4 acc[8][4];
#pragma unroll
  for (int i = 0; i < 8; ++i)
#pragma unroll
    for (int j = 0; j < 4; ++j) acc[i][j] = (f32x4){0.f, 0.f, 0.f, 0.f};

#define STAGE(kh)                                                   \
  do {                                                              \
    const int khs = ((kh) > 23 ? 23 : (kh)) << 5;                   \
    const int so = ((kh) & 3) << 13;                                \
    gl_lds16(gA + khs,         &smem[so + dstc]);                   \
    gl_lds16(gA + 98304 + khs, &smem[so + dstc + 4096]);            \
    gl_lds16(gB + khs,         &smem[32768 + so + dstc]);           \
    gl_lds16(gB + 98304 + khs, &smem[32768 + so + dstc + 4096]);    \
  } while (0)

  STAGE(0); STAGE(1); STAGE(2);

  for (int kh = 0; kh < 24; ++kh) {
    asm volatile("s_waitcnt vmcnt(8)" ::: "memory");   // tile kh landed (12 outstanding - 8)
    __builtin_amdgcn_s_barrier();                      // everyone's tile kh landed; prev reads retired
    __builtin_amdgcn_sched_barrier(0);
    STAGE(kh + 3);                                     // slot (kh+3)&3 == (kh-1)&3: free since barrier
    const u16* pa = &smem[(kh & 3) << 13];
    const u16* pb = pa + 32768;
    short8 bf[4];
#pragma unroll
    for (int nj = 0; nj < 4; ++nj) bf[nj] = *(const short8*)(pb + offB[nj]);
    __builtin_amdgcn_s_setprio(1);
#pragma unroll
    for (int mi = 0; mi < 8; ++mi) {
      const short8 av = *(const short8*)(pa + offA[mi]);
#pragma unroll
      for (int nj = 0; nj < 4; ++nj)
        acc[mi][nj] = __builtin_amdgcn_mfma_f32_16x16x32_bf16(av, bf[nj], acc[mi][nj], 0, 0, 0);
    }
    __builtin_amdgcn_s_setprio(0);
  }
#undef STAGE
  asm volatile("s_waitcnt vmcnt(0)" ::: "memory");  // drain phantom stages

  if (MODE == 0) {
    const int colc = n0 + (wn << 6);        // wave's 64-col window base
    const bool sg = (colc < 1536);          // uniform per wave: q/k vs v
    float jsum[4] = {0.f, 0.f, 0.f, 0.f};
#pragma unroll
    for (int mi = 0; mi < 8; ++mi) {
      const int rowb = m0 + (wm << 7) + (mi << 4) + ((lane >> 4) << 2);
#pragma unroll
      for (int nj = 0; nj < 4; ++nj) {
        const int col = colc + (nj << 4) + r16;
        const float bcol = bias[col];
        if (sg) {
#pragma unroll
          for (int rg = 0; rg < 4; ++rg) {
            const float val = sigm(acc[mi][nj][rg] + bcol);
            jsum[nj] += val;
            qkvo[(size_t)(rowb + rg) * 2304 + col] = f2bfu(val);
          }
        } else {
#pragma unroll
          for (int rg = 0; rg < 4; ++rg)
            qkvo[(size_t)(rowb + rg) * 2304 + col] = f2bfu(acc[mi][nj][rg] + bcol);
        }
      }
    }
    if (sg) {
#pragma unroll
      for (int nj = 0; nj < 4; ++nj) {
        jsum[nj] += __shfl_xor(jsum[nj], 16, 64);
        jsum[nj] += __shfl_xor(jsum[nj], 32, 64);
      }
      if (lane < 16) {
        const int b12 = (m0 >> 12) * 12;
        float* sdst = (colc >= 768) ? ksum : qsum;
        const int cb = (colc >= 768) ? colc - 768 : colc;  // 0..767 = h*64+d
#pragma unroll
        for (int nj = 0; nj < 4; ++nj)
          atomicAdd(&sdst[(b12 << 6) + cb + (nj << 4) + r16], jsum[nj]);
      }
    }
  } else {
#pragma unroll
    for (int mi = 0; mi < 8; ++mi) {
      const int rowb = m0 + (wm << 7) + (mi << 4) + ((lane >> 4) << 2);
#pragma unroll
      for (int nj = 0; nj < 4; ++nj) {
        const int col = n0 + (wn << 6) + (nj << 4) + r16;
        const float bcol = bias[col];
#pragma unroll
        for (int rg = 0; rg < 4; ++rg)
          outf[(size_t)(rowb + rg) * 768 + col] = sigm(2.f * (acc[mi][nj][rg] + bcol));
      }
    }
  }
}

// ---------------- si/so + qsi/kso (flat qkv layout) ----------------
__global__ __launch_bounds__(256) void k_flow1(
    const u16* __restrict__ qkv,
    const float* __restrict__ qsum, const float* __restrict__ ksum,
    float* __restrict__ si_out, float* __restrict__ qsi, float* __restrict__ kso)
{
  const int bh = blockIdx.x >> 3, sp = blockIdx.x & 7;
  const int lane = threadIdx.x & 63, wid = threadIdx.x >> 6;
  const int j = lane & 15;
  const int grp = (wid << 2) | (lane >> 4);
  const u16* base = qkv + (size_t)(bh / 12) * 4096 * 2304 + (bh % 12) * 64;
  float ke[4], qe[4];
#pragma unroll
  for (int t = 0; t < 4; ++t) {
    ke[t] = ksum[(bh << 6) + (j << 2) + t] + EPSF;
    qe[t] = qsum[(bh << 6) + (j << 2) + t] + EPSF;
  }
  float Sk = ke[0] + ke[1] + ke[2] + ke[3];
  float Sq = qe[0] + qe[1] + qe[2] + qe[3];
#pragma unroll
  for (int msk = 1; msk < 16; msk <<= 1) { Sk += __shfl_xor(Sk, msk, 64); Sq += __shfl_xor(Sq, msk, 64); }
  const float cK = EPSF * Sk + EPSF;
  const float cQ = EPSF * Sq + EPSF;
  float aq0 = 0, aq1 = 0, aq2 = 0, aq3 = 0, ak0 = 0, ak1 = 0, ak2 = 0, ak3 = 0;
  const int nbase = sp << 9;
  for (int it = 0; it < 32; ++it) {
    const int n = nbase + (it << 4) + grp;
    const size_t ro = (size_t)n * 2304 + (j << 2);
    const uint64_t lq = *(const uint64_t*)(base + ro);
    const uint64_t lk = *(const uint64_t*)(base + ro + 768);
    const float q0 = us2f((u16)lq), q1 = us2f((u16)(lq >> 16)), q2 = us2f((u16)(lq >> 32)), q3 = us2f((u16)(lq >> 48));
    const float k0 = us2f((u16)lk), k1 = us2f((u16)(lk >> 16)), k2 = us2f((u16)(lk >> 32)), k3 = us2f((u16)(lk >> 48));
    float dq = q0 * ke[0] + q1 * ke[1] + q2 * ke[2] + q3 * ke[3];
    float dk = k0 * qe[0] + k1 * qe[1] + k2 * qe[2] + k3 * qe[3];
#pragma unroll
    for (int msk = 1; msk < 16; msk <<= 1) { dq += __shfl_xor(dq, msk, 64); dk += __shfl_xor(dk, msk, 64); }
    const float si = 1.f / (dq + cK);
    const float so = 1.f / (dk + cQ);
    if (j == 0) si_out[(bh << 12) + n] = si;
    aq0 += q0 * si; aq1 += q1 * si; aq2 += q2 * si; aq3 += q3 * si;
    ak0 += k0 * so; ak1 += k1 * so; ak2 += k2 * so; ak3 += k3 * so;
  }
  __shared__ float redq[16][64];
  __shared__ float redk[16][64];
  redq[grp][(j << 2) + 0] = aq0; redq[grp][(j << 2) + 1] = aq1;
  redq[grp][(j << 2) + 2] = aq2; redq[grp][(j << 2) + 3] = aq3;
  redk[grp][(j << 2) + 0] = ak0; redk[grp][(j << 2) + 1] = ak1;
  redk[grp][(j << 2) + 2] = ak2; redk[grp][(j << 2) + 3] = ak3;
  __syncthreads();
  if (threadIdx.x < 64) {
    float s1 = 0.f, s2 = 0.f;
#pragma unroll
    for (int g = 0; g < 16; ++g) { s1 += redq[g][threadIdx.x]; s2 += redk[g][threadIdx.x]; }
    atomicAdd(&qsi[(bh << 6) + threadIdx.x], s1);
    atomicAdd(&kso[(bh << 6) + threadIdx.x], s2);
  }
}

// ---------------- fused flow2 + kv (MFMA): e/m/sumexp inline, kvm[d][e] accumulate ----------------
__global__ __launch_bounds__(256) void k_fkv(
    const u16* __restrict__ qkv,
    const float* __restrict__ qsi, const float* __restrict__ kso,
    const float* __restrict__ si_in,
    float* __restrict__ mo, float* __restrict__ sumexp, float* __restrict__ kvm)
{
  __shared__ __align__(16) u16 smem[2 * 64 * 136];  // 34816 B; reused as f32 reduce buf
  u16* kT = smem;
  u16* vT = smem + 64 * 136;
  const int tid = threadIdx.x;
  const int bh = blockIdx.x >> 3, sp = blockIdx.x & 7;
  const int lane = tid & 63, wid = tid >> 6;
  const int r16 = lane & 15, g = lane >> 4;
  const u16* base = qkv + (size_t)(bh / 12) * 4096 * 2304 + (bh % 12) * 64;
  const float* sib = si_in + ((size_t)bh << 12);
  float* mob = mo + ((size_t)bh << 12);

  // per-thread d-slice (constant across stages/iters)
  const int d0 = (tid & 7) << 3;
  float qie[8], soe[8];
#pragma unroll
  for (int u = 0; u < 8; ++u) {
    qie[u] = qsi[(bh << 6) + d0 + u] + EPSF;
    soe[u] = kso[(bh << 6) + d0 + u] + EPSF;
  }
  // block-uniform eps terms: cR = eps*sum(qsi+eps)+eps, cS = eps*sum(kso+eps)+eps
  float Sq = qsi[(bh << 6) + lane] + EPSF;
  float Sk = kso[(bh << 6) + lane] + EPSF;
#pragma unroll
  for (int m = 1; m < 64; m <<= 1) { Sq += __shfl_xor(Sq, m, 64); Sk += __shfl_xor(Sk, m, 64); }
  const float cR = EPSF * Sq + EPSF;
  const float cS = EPSF * Sk + EPSF;

  f32x4 acc[4][4];
#pragma unroll
  for (int i = 0; i < 4; ++i)
#pragma unroll
    for (int j = 0; j < 4; ++j) acc[i][j] = (f32x4){0.f, 0.f, 0.f, 0.f};

  const int nf = (wid << 5) + (g << 3);  // wave n-window + lane-group k offset
  float esum = 0.f;

  for (int st = 0; st < 4; ++st) {
    const int nst = (sp << 9) + (st << 7);
#pragma unroll
    for (int i = 0; i < 4; ++i) {
      const int c = tid + (i << 8);
      const int nl = c >> 3;              // 0..127
      const int ng = nst + nl;
      const u16* rp = base + (size_t)ng * 2304 + d0;
      short8 q8 = *(const short8*)(rp);
      short8 k8 = *(const short8*)(rp + 768);
      short8 v8 = *(const short8*)(rp + 1536);
      float pcs = 0.f, pcr = 0.f;
#pragma unroll
      for (int u = 0; u < 8; ++u) {
        pcs += us2f((u16)q8[u]) * soe[u];
        pcr += us2f((u16)k8[u]) * qie[u];
      }
#pragma unroll
      for (int m = 1; m < 8; m <<= 1) { pcs += __shfl_xor(pcs, m, 64); pcr += __shfl_xor(pcr, m, 64); }
      float cr = pcr + cR;
      cr = fminf(1.f, fmaxf(-1.f, cr));
      const float ev = __expf(cr);
      const int col = nl ^ (d0 & 56);     // write-side XOR swizzle (proven, round 3)
#pragma unroll
      for (int u = 0; u < 8; ++u) {
        kT[(d0 + u) * 136 + col] = f2bfu(us2f((u16)k8[u]) * ev);
        vT[(d0 + u) * 136 + col] = (u16)(unsigned short)v8[u];
      }
      if ((tid & 7) == 0) {
        mob[ng] = sib[ng] * sigm(pcs + cS);
        esum += ev;
      }
    }
    __syncthreads();

    short8 af[4], bf[4];
#pragma unroll
    for (int mi = 0; mi < 4; ++mi) {
      const int row = (mi << 4) + r16;
      af[mi] = *(const short8*)&kT[row * 136 + (nf ^ (row & 56))];
    }
#pragma unroll
    for (int nj = 0; nj < 4; ++nj) {
      const int row = (nj << 4) + r16;
      bf[nj] = *(const short8*)&vT[row * 136 + (nf ^ (row & 56))];
    }
#pragma unroll
    for (int mi = 0; mi < 4; ++mi)
#pragma unroll
      for (int nj = 0; nj < 4; ++nj)
        acc[mi][nj] = __builtin_amdgcn_mfma_f32_16x16x32_bf16(af[mi], bf[nj], acc[mi][nj], 0, 0, 0);
    __syncthreads();
  }

  // cross-wave reduce (two 32-d halves through LDS) + coalesced atomics
  float* red = (float*)smem;
  float* kvb = kvm + ((size_t)bh << 12);
#pragma unroll
  for (int half = 0; half < 2; ++half) {
#pragma unroll
    for (int m2 = 0; m2 < 2; ++m2) {
      const int mi = (half << 1) + m2;
#pragma unroll
      for (int nj = 0; nj < 4; ++nj)
#pragma unroll
        for (int rg = 0; rg < 4; ++rg)
          red[(wid << 11) + (((m2 << 4) + (g << 2) + rg) << 6) + (nj << 4) + r16] = acc[mi][nj][rg];
    }
    __syncthreads();
    const int base2 = tid << 3;
#pragma unroll
    for (int u2 = 0; u2 < 2; ++u2) {
      const int o = base2 + (u2 << 2);
      float4 s0 = *(const float4*)&red[o];
      float4 s1 = *(const float4*)&red[2048 + o];
      float4 s2 = *(const float4*)&red[4096 + o];
      float4 s3 = *(const float4*)&red[6144 + o];
      s0.x += s1.x + s2.x + s3.x;
      s0.y += s1.y + s2.y + s3.y;
      s0.z += s1.z + s2.z + s3.z;
      s0.w += s1.w + s2.w + s3.w;
      const int gi = (half << 11) + o;
      atomicAdd(&kvb[gi + 0], s0.x);
      atomicAdd(&kvb[gi + 1], s0.y);
      atomicAdd(&kvb[gi + 2], s0.z);
      atomicAdd(&kvb[gi + 3], s0.w);
    }
    __syncthreads();
  }

  // sumexp: lanes 0,8,...,56 hold partials; fold within wave, 1 atomic/wave
  esum += __shfl_xor(esum, 8, 64);
  esum += __shfl_xor(esum, 16, 64);
  esum += __shfl_xor(esum, 32, 64);
  if (lane == 0) atomicAdd(&sumexp[bh], esum);
}

// ---------------- x_update = (q @ kv) * m[n] * scale -> attn [B][N][C] bf16 (MFMA) ----------------
__global__ __launch_bounds__(256) void k_xup(
    const u16* __restrict__ qkv, const float* __restrict__ kvm,
    const float* __restrict__ m_arr, const float* __restrict__ sumexp,
    u16* __restrict__ attn)
{
  const int bh = blockIdx.y;
  const int n0 = blockIdx.x << 7;
  const int b = bh / 12, h = bh % 12;
  __shared__ __align__(16) u16 qs[128 * 72];   // stride 72 elems (144B): 2-way banks, 16B aligned
  __shared__ __align__(16) u16 kvs[64 * 72];   // kv^T as [e][d] bf16
  const int tid = threadIdx.x, lane = tid & 63, wid = tid >> 6;
  const u16* qg = qkv + (size_t)b * 4096 * 2304 + (size_t)n0 * 2304 + h * 64;
#pragma unroll
  for (int i = 0; i < 4; ++i) {
    const int c = tid + (i << 8);
    const int nl = c >> 3, d0 = (c & 7) << 3;
    *(short8*)&qs[nl * 72 + d0] = *(const short8*)(qg + (size_t)nl * 2304 + d0);
  }
  const float* kvg = kvm + ((size_t)bh << 12);
#pragma unroll
  for (int i = 0; i < 4; ++i) {
    const int idx = (tid << 2) + (i << 10);
    const int d = idx >> 6, e0 = idx & 63;
    float4 vv = *(const float4*)(kvg + idx);
    kvs[(e0 + 0) * 72 + d] = f2bfu(vv.x);
    kvs[(e0 + 1) * 72 + d] = f2bfu(vv.y);
    kvs[(e0 + 2) * 72 + d] = f2bfu(vv.z);
    kvs[(e0 + 3) * 72 + d] = f2bfu(vv.w);
  }
  __syncthreads();
  const float scale = 4096.f / sumexp[bh];
  const int r16 = lane & 15, kg8 = (lane >> 4) << 3;
  f32x4 acc[2][4];
#pragma unroll
  for (int i = 0; i < 2; ++i)
#pragma unroll
    for (int j = 0; j < 4; ++j) acc[i][j] = (f32x4){0.f, 0.f, 0.f, 0.f};
#pragma unroll
  for (int kk = 0; kk < 2; ++kk) {
    short8 af[2], bfv[4];
#pragma unroll
    for (int mi = 0; mi < 2; ++mi)
      af[mi] = *(const short8*)&qs[((wid << 5) + (mi << 4) + r16) * 72 + (kk << 5) + kg8];
#pragma unroll
    for (int nj = 0; nj < 4; ++nj)
      bfv[nj] = *(const short8*)&kvs[((nj << 4) + r16) * 72 + (kk << 5) + kg8];
#pragma unroll
    for (int mi = 0; mi < 2; ++mi)
#pragma unroll
      for (int nj = 0; nj < 4; ++nj)
        acc[mi][nj] = __builtin_amdgcn_mfma_f32_16x16x32_bf16(af[mi], bfv[nj], acc[mi][nj], 0, 0, 0);
  }
#pragma unroll
  for (int mi = 0; mi < 2; ++mi) {
#pragma unroll
    for (int rg = 0; rg < 4; ++rg) {
      const int n = n0 + (wid << 5) + (mi << 4) + ((lane >> 4) << 2) + rg;
      const float mult = m_arr[((size_t)bh << 12) + n] * scale;
#pragma unroll
      for (int nj = 0; nj < 4; ++nj) {
        const int e = (nj << 4) + r16;
        attn[((size_t)(b * 4096 + n)) * 768 + (h << 6) + e] = f2bfu(acc[mi][nj][rg] * mult);
      }
    }
  }
}

extern "C" void kernel_launch(void* const* d_in, const int* in_sizes, int n_in,
                              void* d_out, int out_size, void* d_ws, size_t ws_size,
                              hipStream_t stream)
{
  (void)in_sizes; (void)n_in; (void)out_size; (void)ws_size;
  const float* x     = (const float*)d_in[0];
  const float* Wqkv  = (const float*)d_in[1];
  const float* bqkv  = (const float*)d_in[2];
  const float* Wproj = (const float*)d_in[3];
  const float* bproj = (const float*)d_in[4];
  float* out = (float*)d_out;

  char* ws = (char*)d_ws;
  size_t off = 0;
  auto alloc = [&](size_t bytes) -> char* {
    char* p = ws + off;
    off += (bytes + 255) & ~(size_t)255;
    return p;
  };
  u16* qkv  = (u16*)alloc(150994944);      // [32768][2304] bf16 flat (q|k|v)
  u16* xbf  = (u16*)alloc(50331648);       // x bf16; reused as attn output
  u16* WqT  = (u16*)alloc(3538944);        // [2304][768] bf16
  u16* WpT  = (u16*)alloc(1179648);        // [768][768] bf16
  float* si = (float*)alloc(1572864);      // [B*H][N]
  float* mb = (float*)alloc(1572864);      // si * sink_allocation
  char* zbase = ws + off;
  float* qsum   = (float*)alloc(24576);
  float* ksum   = (float*)alloc(24576);
  float* qsi    = (float*)alloc(24576);
  float* kso    = (float*)alloc(24576);
  float* sumexp = (float*)alloc(512);
  float* kvm    = (float*)alloc(1572864);  // [B*H][64 d][64 e] f32
  const size_t zbytes = (size_t)((ws + off) - zbase);

  hipMemsetAsync(zbase, 0, zbytes, stream);
  k_cvt_x<<<24576, 256, 0, stream>>>(x, xbf);
  k_transpose<<<dim3(72, 24), 256, 0, stream>>>(Wqkv, WqT, 768, 2304);
  k_transpose<<<dim3(24, 24), 256, 0, stream>>>(Wproj, WpT, 768, 768);
  k_gemm<0><<<dim3(9, 128), 512, 0, stream>>>(xbf, WqT, bqkv, qkv, qsum, ksum, nullptr);
  k_flow1<<<768, 256, 0, stream>>>(qkv, qsum, ksum, si, qsi, kso);
  k_fkv<<<768, 256, 0, stream>>>(qkv, qsi, kso, si, mb, sumexp, kvm);
  k_xup<<<dim3(32, 96), 256, 0, stream>>>(qkv, kvm, mb, sumexp, xbf);
  k_gemm<1><<<dim3(3, 128), 512, 0, stream>>>(xbf, WpT, bproj, nullptr, nullptr, nullptr, out);
}